// Round 9
// baseline (412.308 us; speedup 1.0000x reference)
//
#include <hip/hip_runtime.h>
#include <hip/hip_bf16.h>

typedef unsigned short u16;
typedef short bf16x8 __attribute__((ext_vector_type(8)));
typedef float f32x4 __attribute__((ext_vector_type(4)));

#define T_DIM 2048
#define C_DIM 2048
#define F_DIM 8192
#define WKV_L 32
#define WKV_P (T_DIM / WKV_L)   // 64 chunks

// ---------- helpers ----------
__device__ __forceinline__ u16 f2bf(float f) {
    unsigned int u = __float_as_uint(f);
    u += 0x7fff + ((u >> 16) & 1);          // round-to-nearest-even
    return (u16)(u >> 16);
}

__device__ __forceinline__ void async16(const void* g, void* l) {
    __builtin_amdgcn_global_load_lds(
        (__attribute__((address_space(1))) const unsigned int*)g,
        (__attribute__((address_space(3))) unsigned int*)l, 16, 0, 0);
}

// ---------- fused LayerNorm + token-shift mix (3 outputs) ----------
__global__ __launch_bounds__(256) void ln_mix3(
        const float* __restrict__ x, const float* __restrict__ sh,
        const float* __restrict__ w, const float* __restrict__ b,
        const float* __restrict__ mk, const float* __restrict__ mv,
        const float* __restrict__ mr,
        u16* __restrict__ xk, u16* __restrict__ xv, u16* __restrict__ xr) {
    __shared__ float red[16];
    const int t = blockIdx.x, tid = threadIdx.x;
    const float4* cr = (const float4*)(x + (size_t)t * C_DIM);
    float4 c0 = cr[tid * 2], c1 = cr[tid * 2 + 1];
    float s = c0.x + c0.y + c0.z + c0.w + c1.x + c1.y + c1.z + c1.w;
    float q = c0.x * c0.x + c0.y * c0.y + c0.z * c0.z + c0.w * c0.w
            + c1.x * c1.x + c1.y * c1.y + c1.z * c1.z + c1.w * c1.w;
    float4 p0, p1;
    float sp = 0.f, qp = 0.f;
    if (t > 0) {
        const float4* pr = (const float4*)(x + (size_t)(t - 1) * C_DIM);
        p0 = pr[tid * 2]; p1 = pr[tid * 2 + 1];
        sp = p0.x + p0.y + p0.z + p0.w + p1.x + p1.y + p1.z + p1.w;
        qp = p0.x * p0.x + p0.y * p0.y + p0.z * p0.z + p0.w * p0.w
           + p1.x * p1.x + p1.y * p1.y + p1.z * p1.z + p1.w * p1.w;
    } else {
        const float4* pr = (const float4*)sh;
        p0 = pr[tid * 2]; p1 = pr[tid * 2 + 1];
    }
    #pragma unroll
    for (int off = 32; off > 0; off >>= 1) {
        s += __shfl_down(s, off);   q += __shfl_down(q, off);
        sp += __shfl_down(sp, off); qp += __shfl_down(qp, off);
    }
    const int lane = tid & 63, wv = tid >> 6;
    if (lane == 0) { red[wv] = s; red[4 + wv] = q; red[8 + wv] = sp; red[12 + wv] = qp; }
    __syncthreads();
    if (tid == 0) {
        red[0] += red[1] + red[2] + red[3];
        red[4] += red[5] + red[6] + red[7];
        red[8] += red[9] + red[10] + red[11];
        red[12] += red[13] + red[14] + red[15];
    }
    __syncthreads();
    const float mc = red[0] * (1.f / C_DIM);
    const float ic = rsqrtf(red[4] * (1.f / C_DIM) - mc * mc + 1e-5f);
    const float mp = red[8] * (1.f / C_DIM);
    const float ip = rsqrtf(red[12] * (1.f / C_DIM) - mp * mp + 1e-5f);
    const float4* w4 = (const float4*)w;
    const float4* b4 = (const float4*)b;
    #pragma unroll
    for (int j = 0; j < 2; ++j) {
        const int i4 = tid * 2 + j;
        float4 cv = j ? c1 : c0, pv = j ? p1 : p0;
        float4 wv4 = w4[i4], bv = b4[i4];
        float4 cl, pl;
        cl.x = (cv.x - mc) * ic * wv4.x + bv.x;
        cl.y = (cv.y - mc) * ic * wv4.y + bv.y;
        cl.z = (cv.z - mc) * ic * wv4.z + bv.z;
        cl.w = (cv.w - mc) * ic * wv4.w + bv.w;
        if (t > 0) {
            pl.x = (pv.x - mp) * ip * wv4.x + bv.x;
            pl.y = (pv.y - mp) * ip * wv4.y + bv.y;
            pl.z = (pv.z - mp) * ip * wv4.z + bv.z;
            pl.w = (pv.w - mp) * ip * wv4.w + bv.w;
        } else pl = pv;
        const size_t o = (size_t)t * (C_DIM / 4) + i4;
        float4 m;
        ushort4 r;
        m = ((const float4*)mk)[i4];
        r.x = f2bf(cl.x * m.x + pl.x * (1.f - m.x));
        r.y = f2bf(cl.y * m.y + pl.y * (1.f - m.y));
        r.z = f2bf(cl.z * m.z + pl.z * (1.f - m.z));
        r.w = f2bf(cl.w * m.w + pl.w * (1.f - m.w));
        ((ushort4*)xk)[o] = r;
        m = ((const float4*)mv)[i4];
        r.x = f2bf(cl.x * m.x + pl.x * (1.f - m.x));
        r.y = f2bf(cl.y * m.y + pl.y * (1.f - m.y));
        r.z = f2bf(cl.z * m.z + pl.z * (1.f - m.z));
        r.w = f2bf(cl.w * m.w + pl.w * (1.f - m.w));
        ((ushort4*)xv)[o] = r;
        m = ((const float4*)mr)[i4];
        r.x = f2bf(cl.x * m.x + pl.x * (1.f - m.x));
        r.y = f2bf(cl.y * m.y + pl.y * (1.f - m.y));
        r.z = f2bf(cl.z * m.z + pl.z * (1.f - m.z));
        r.w = f2bf(cl.w * m.w + pl.w * (1.f - m.w));
        ((ushort4*)xr)[o] = r;
    }
}

// ---------- fused LayerNorm + token-shift mix (2 outputs) ----------
__global__ __launch_bounds__(256) void ln_mix2(
        const float* __restrict__ x, const float* __restrict__ sh,
        const float* __restrict__ w, const float* __restrict__ b,
        const float* __restrict__ mk, const float* __restrict__ mr,
        u16* __restrict__ fk, u16* __restrict__ fr) {
    __shared__ float red[16];
    const int t = blockIdx.x, tid = threadIdx.x;
    const float4* cr = (const float4*)(x + (size_t)t * C_DIM);
    float4 c0 = cr[tid * 2], c1 = cr[tid * 2 + 1];
    float s = c0.x + c0.y + c0.z + c0.w + c1.x + c1.y + c1.z + c1.w;
    float q = c0.x * c0.x + c0.y * c0.y + c0.z * c0.z + c0.w * c0.w
            + c1.x * c1.x + c1.y * c1.y + c1.z * c1.z + c1.w * c1.w;
    float4 p0, p1;
    float sp = 0.f, qp = 0.f;
    if (t > 0) {
        const float4* pr = (const float4*)(x + (size_t)(t - 1) * C_DIM);
        p0 = pr[tid * 2]; p1 = pr[tid * 2 + 1];
        sp = p0.x + p0.y + p0.z + p0.w + p1.x + p1.y + p1.z + p1.w;
        qp = p0.x * p0.x + p0.y * p0.y + p0.z * p0.z + p0.w * p0.w
           + p1.x * p1.x + p1.y * p1.y + p1.z * p1.z + p1.w * p1.w;
    } else {
        const float4* pr = (const float4*)sh;
        p0 = pr[tid * 2]; p1 = pr[tid * 2 + 1];
    }
    #pragma unroll
    for (int off = 32; off > 0; off >>= 1) {
        s += __shfl_down(s, off);   q += __shfl_down(q, off);
        sp += __shfl_down(sp, off); qp += __shfl_down(qp, off);
    }
    const int lane = tid & 63, wv = tid >> 6;
    if (lane == 0) { red[wv] = s; red[4 + wv] = q; red[8 + wv] = sp; red[12 + wv] = qp; }
    __syncthreads();
    if (tid == 0) {
        red[0] += red[1] + red[2] + red[3];
        red[4] += red[5] + red[6] + red[7];
        red[8] += red[9] + red[10] + red[11];
        red[12] += red[13] + red[14] + red[15];
    }
    __syncthreads();
    const float mc = red[0] * (1.f / C_DIM);
    const float ic = rsqrtf(red[4] * (1.f / C_DIM) - mc * mc + 1e-5f);
    const float mp = red[8] * (1.f / C_DIM);
    const float ip = rsqrtf(red[12] * (1.f / C_DIM) - mp * mp + 1e-5f);
    const float4* w4 = (const float4*)w;
    const float4* b4 = (const float4*)b;
    #pragma unroll
    for (int j = 0; j < 2; ++j) {
        const int i4 = tid * 2 + j;
        float4 cv = j ? c1 : c0, pv = j ? p1 : p0;
        float4 wv4 = w4[i4], bv = b4[i4];
        float4 cl, pl;
        cl.x = (cv.x - mc) * ic * wv4.x + bv.x;
        cl.y = (cv.y - mc) * ic * wv4.y + bv.y;
        cl.z = (cv.z - mc) * ic * wv4.z + bv.z;
        cl.w = (cv.w - mc) * ic * wv4.w + bv.w;
        if (t > 0) {
            pl.x = (pv.x - mp) * ip * wv4.x + bv.x;
            pl.y = (pv.y - mp) * ip * wv4.y + bv.y;
            pl.z = (pv.z - mp) * ip * wv4.z + bv.z;
            pl.w = (pv.w - mp) * ip * wv4.w + bv.w;
        } else pl = pv;
        const size_t o = (size_t)t * (C_DIM / 4) + i4;
        float4 m;
        ushort4 r;
        m = ((const float4*)mk)[i4];
        r.x = f2bf(cl.x * m.x + pl.x * (1.f - m.x));
        r.y = f2bf(cl.y * m.y + pl.y * (1.f - m.y));
        r.z = f2bf(cl.z * m.z + pl.z * (1.f - m.z));
        r.w = f2bf(cl.w * m.w + pl.w * (1.f - m.w));
        ((ushort4*)fk)[o] = r;
        m = ((const float4*)mr)[i4];
        r.x = f2bf(cl.x * m.x + pl.x * (1.f - m.x));
        r.y = f2bf(cl.y * m.y + pl.y * (1.f - m.y));
        r.z = f2bf(cl.z * m.z + pl.z * (1.f - m.z));
        r.w = f2bf(cl.w * m.w + pl.w * (1.f - m.w));
        ((ushort4*)fr)[o] = r;
    }
}

// ---------- f32 -> bf16 conversion ----------
__global__ __launch_bounds__(256) void cvt_bf16(const float* __restrict__ in,
                                                u16* __restrict__ out, int n8) {
    int i = blockIdx.x * 256 + threadIdx.x;
    const int stride = gridDim.x * 256;
    for (; i < n8; i += stride) {
        const float4* p = (const float4*)(in + (size_t)i * 8);
        float4 a = p[0], b = p[1];
        ushort4 lo, hi;
        lo.x = f2bf(a.x); lo.y = f2bf(a.y); lo.z = f2bf(a.z); lo.w = f2bf(a.w);
        hi.x = f2bf(b.x); hi.y = f2bf(b.y); hi.z = f2bf(b.z); hi.w = f2bf(b.w);
        ((ushort4*)out)[i * 2] = lo;
        ((ushort4*)out)[i * 2 + 1] = hi;
    }
}

// four C*C weights in one launch (blockIdx.y selects the array)
__global__ __launch_bounds__(256) void cvt4_bf16(const float* __restrict__ i0,
                                                 const float* __restrict__ i1,
                                                 const float* __restrict__ i2,
                                                 const float* __restrict__ i3,
                                                 u16* __restrict__ out, int n8) {
    const int sel = blockIdx.y;
    const float* in = sel == 0 ? i0 : (sel == 1 ? i1 : (sel == 2 ? i2 : i3));
    u16* o = out + (size_t)sel * n8 * 8;
    int i = blockIdx.x * 256 + threadIdx.x;
    const int stride = gridDim.x * 256;
    for (; i < n8; i += stride) {
        const float4* p = (const float4*)(in + (size_t)i * 8);
        float4 a = p[0], b = p[1];
        ushort4 lo, hi;
        lo.x = f2bf(a.x); lo.y = f2bf(a.y); lo.z = f2bf(a.z); lo.w = f2bf(a.w);
        hi.x = f2bf(b.x); hi.y = f2bf(b.y); hi.z = f2bf(b.z); hi.w = f2bf(b.w);
        ((ushort4*)o)[i * 2] = lo;
        ((ushort4*)o)[i * 2 + 1] = hi;
    }
}

// ---------- 2-way partial-sum reduce (float4) ----------
__global__ __launch_bounds__(256) void reduce2(const float* __restrict__ p0,
                                               const float* __restrict__ p1,
                                               float* __restrict__ o, int n4) {
    int i = blockIdx.x * 256 + threadIdx.x;
    const int stride = gridDim.x * 256;
    for (; i < n4; i += stride) {
        float4 a = ((const float4*)p0)[i], b = ((const float4*)p1)[i];
        float4 r;
        r.x = a.x + b.x;
        r.y = a.y + b.y;
        r.z = a.z + b.z;
        r.w = a.w + b.w;
        ((float4*)o)[i] = r;
    }
}

// ---------- WKV parallel scan ----------
__global__ __launch_bounds__(256) void wkv_part(const float* __restrict__ td,
                                                const float* __restrict__ k,
                                                const float* __restrict__ v,
                                                float* __restrict__ Ab,
                                                float* __restrict__ Bb) {
    const int idx = blockIdx.x * 256 + threadIdx.x;     // C*P threads
    const int c = idx & (C_DIM - 1);
    const int p = idx >> 11;
    const float ew = expf(-expf(td[c]));
    float A = 0.f, B = 0.f;
    size_t o = (size_t)(p * WKV_L) * C_DIM + c;
    #pragma unroll 4
    for (int i = 0; i < WKV_L; ++i, o += C_DIM) {
        const float kk = expf(k[o]);
        A = (A + kk * v[o]) * ew;
        B = (B + kk) * ew;
    }
    Ab[p * C_DIM + c] = A;
    Bb[p * C_DIM + c] = B;
}

__global__ __launch_bounds__(256) void wkv_comb(const float* __restrict__ td,
                                                const float* __restrict__ st,
                                                const float* __restrict__ Ab,
                                                const float* __restrict__ Bb,
                                                float* __restrict__ Sa,
                                                float* __restrict__ Sb) {
    const int c = blockIdx.x * 256 + threadIdx.x;       // C threads
    const float w = -expf(td[c]);
    const float dL = expf(w * (float)WKV_L);            // ew^L
    float a = st[c];
    float b = st[C_DIM + c];
    #pragma unroll 4
    for (int p = 0; p < WKV_P; ++p) {
        Sa[p * C_DIM + c] = a;
        Sb[p * C_DIM + c] = b;
        a = dL * a + Ab[p * C_DIM + c];
        b = dL * b + Bb[p * C_DIM + c];
    }
}

__global__ __launch_bounds__(256) void wkv_emit(const float* __restrict__ td,
                                                const float* __restrict__ tf,
                                                const float* __restrict__ k,
                                                const float* __restrict__ v,
                                                const float* __restrict__ r,
                                                const float* __restrict__ Sa,
                                                const float* __restrict__ Sb,
                                                u16* __restrict__ pout) {
    const int idx = blockIdx.x * 256 + threadIdx.x;     // C*P threads
    const int c = idx & (C_DIM - 1);
    const int p = idx >> 11;
    const float u = tf[c];
    const float w = -expf(td[c]);
    const float ew = expf(w);
    float a = Sa[p * C_DIM + c];
    float b = Sb[p * C_DIM + c];
    size_t o = (size_t)(p * WKV_L) * C_DIM + c;
    #pragma unroll 2
    for (int i = 0; i < WKV_L; ++i, o += C_DIM) {
        const float kt = k[o], vt = v[o], rt = r[o];
        const float e = expf(u + w + kt);
        const float y = (a + e * vt) / (b + e);
        const float kk = expf(kt);
        a = (a + kk * vt) * ew;
        b = (b + kk) * ew;
        const float sr = 1.f / (1.f + expf(-rt));
        pout[o] = f2bf(sr * y);
    }
}

enum { EPI_F32 = 0, EPI_ADDX = 1, EPI_RELU2 = 2, EPI_SIGMULADD = 3 };

// ---------- 128x128 bf16 NT GEMM — 3-slot pipeline, 3 blocks/CU ----------
// BK=32, 64B LDS rows + bit9-XOR swizzle (0 conflicts, verified R8), counted
// vmcnt (never drained in-loop), 4 waves (2Mx2N, 64x64 out each).
// LDS 48 KiB -> 3 blocks/CU = 12 waves/CU (R8's 4-slot/64KB capped at 2).
// Pipeline: prologue stages tiles 0,1 (8 loads). Iter t: vmcnt(4) [tile t
// landed, t+1 in flight], barrier, stage tile t+2 into slot (t+2)%3 =
// (t-1)%3 (its readers' lgkm drained before their MFMAs, which precede this
// barrier), read slot t%3, 32 MFMA.
// z-dim: batch via a_zs/b_zs/o_zs, or split-K via koff (element offset).
template <int EPI>
__global__ __launch_bounds__(256, 3) void gemm_bt(
        const u16* __restrict__ A, int lda, long a_zs,
        const u16* __restrict__ B, int ldb, long b_zs,
        long koff, int Kloop,
        void* __restrict__ outp, int ldo, long o_zs,
        const float* __restrict__ aux1, const float* __restrict__ aux2) {
    __shared__ u16 lds[3 * 8192];   // 48 KiB: 3 slots x (A 8KB + B 8KB)
    const int tid = threadIdx.x;
    const int l = tid & 63, w = tid >> 6;
    const int wr2 = w >> 1, wc2 = w & 1;     // 2x2 waves of 64x64

    // bijective XCD remap, bn-major (nwg % 8 == 0 for all launches here)
    const int gx = gridDim.x, gy = gridDim.y;
    const int nxy = gx * gy;
    const int flat = (blockIdx.z * gy + blockIdx.y) * gx + blockIdx.x;
    const int cpx = (nxy * gridDim.z) >> 3;
    const int swz = (flat & 7) * cpx + (flat >> 3);
    const int z = swz / nxy;
    const int rem = swz - z * nxy;
    const int bm = rem % gy;          // consecutive swz share bn (B-panel)
    const int bn = rem / gy;

    const u16* Ag = A + (size_t)z * a_zs + (size_t)z * koff + (size_t)bm * 128 * lda;
    const u16* Bg = B + (size_t)z * b_zs + (size_t)z * koff + (size_t)bn * 128 * ldb;

    // staging: pre-swizzled global source, linear LDS dest (wave-uniform+lane*16)
    long gA[2], gB[2];
    int dA[2], dB[2];
    #pragma unroll
    for (int j = 0; j < 2; ++j) {
        const int off = j * 4096 + w * 1024 + l * 16;   // byte off in 8KB region
        const int row = off >> 6;                        // 64B rows (32 elems)
        const int cb = (off & 63) ^ (((off >> 9) & 1) << 5);
        gA[j] = (long)row * lda + (cb >> 1);
        gB[j] = (long)row * ldb + (cb >> 1);
        dA[j] = j * 2048 + w * 512;          // element index, wave-uniform
        dB[j] = 4096 + j * 2048 + w * 512;
    }

    // ds_read fragment offsets (swizzled), element index within slot
    int offA[4], offB[4];
    #pragma unroll
    for (int m = 0; m < 4; ++m) {
        const int lin = (wr2 * 64 + m * 16 + (l & 15)) * 64 + ((l >> 4) << 4);
        offA[m] = (lin ^ (((lin >> 9) & 1) << 5)) >> 1;
    }
    #pragma unroll
    for (int n = 0; n < 4; ++n) {
        const int lin = (wc2 * 64 + n * 16 + (l & 15)) * 64 + ((l >> 4) << 4);
        offB[n] = 4096 + ((lin ^ (((lin >> 9) & 1) << 5)) >> 1);
    }

    const f32x4 fz = {0.f, 0.f, 0.f, 0.f};
    f32x4 acc[4][4];
    #pragma unroll
    for (int m = 0; m < 4; ++m)
        #pragma unroll
        for (int n = 0; n < 4; ++n) acc[m][n] = fz;

    const int NT = Kloop >> 5;

    auto stage = [&](int kt, int sp) {
        const long ko = (long)kt << 5;
        const int sb = sp * 8192;
        async16(Ag + gA[0] + ko, &lds[sb + dA[0]]);
        async16(Ag + gA[1] + ko, &lds[sb + dA[1]]);
        async16(Bg + gB[0] + ko, &lds[sb + dB[0]]);
        async16(Bg + gB[1] + ko, &lds[sb + dB[1]]);
    };

    // prologue: tiles 0,1 -> slots 0,1 (8 loads outstanding)
    stage(0, 0);
    stage(1, 1);

    int sr = 0;                         // read slot = t % 3
    for (int t = 0; t < NT; ++t) {
        // wait: tile t landed (<=4 outstanding = tile t+1's loads)
        asm volatile("s_waitcnt vmcnt(4)" ::: "memory");
        __builtin_amdgcn_s_barrier();
        __builtin_amdgcn_sched_barrier(0);
        {
            const int tp = (t + 2 < NT) ? t + 2 : NT - 1;
            const int sp = (sr == 0) ? 2 : sr - 1;   // (t+2)%3 == (t-1)%3
            stage(tp, sp);
        }
        const int sb = sr * 8192;
        bf16x8 af[4], bfv[4];
        #pragma unroll
        for (int m = 0; m < 4; ++m) af[m] = *(const bf16x8*)&lds[sb + offA[m]];
        #pragma unroll
        for (int n = 0; n < 4; ++n) bfv[n] = *(const bf16x8*)&lds[sb + offB[n]];
        __builtin_amdgcn_s_setprio(1);
        #pragma unroll
        for (int m = 0; m < 2; ++m)
            #pragma unroll
            for (int n = 0; n < 4; ++n)
                acc[m][n] = __builtin_amdgcn_mfma_f32_16x16x32_bf16(af[m], bfv[n], acc[m][n], 0, 0, 0);
        __builtin_amdgcn_s_setprio(0);
        __builtin_amdgcn_s_setprio(1);
        #pragma unroll
        for (int m = 2; m < 4; ++m)
            #pragma unroll
            for (int n = 0; n < 4; ++n)
                acc[m][n] = __builtin_amdgcn_mfma_f32_16x16x32_bf16(af[m], bfv[n], acc[m][n], 0, 0, 0);
        __builtin_amdgcn_s_setprio(0);
        sr = (sr == 2) ? 0 : sr + 1;
    }
    asm volatile("s_waitcnt vmcnt(0)" ::: "memory");  // drain tail stages

    // --- epilogue ---
    const int r00 = bm * 128 + wr2 * 64 + ((l >> 4) << 2);
    const int c00 = bn * 128 + wc2 * 64 + (l & 15);
    #pragma unroll
    for (int m = 0; m < 4; ++m) {
        #pragma unroll
        for (int n = 0; n < 4; ++n) {
            #pragma unroll
            for (int j = 0; j < 4; ++j) {
                const int rr = r00 + m * 16 + j;
                const int cc = c00 + n * 16;
                const size_t o = (size_t)rr * ldo + cc;
                const float val = acc[m][n][j];
                if constexpr (EPI == EPI_F32) {
                    ((float*)outp)[(size_t)z * o_zs + o] = val;
                } else if constexpr (EPI == EPI_ADDX) {
                    ((float*)outp)[o] = aux1[o] + val;
                } else if constexpr (EPI == EPI_RELU2) {
                    const float tp2 = fmaxf(val, 0.f);
                    ((u16*)outp)[o] = f2bf(tp2 * tp2);
                } else {  // EPI_SIGMULADD
                    const float sg = 1.f / (1.f + expf(-val));
                    ((float*)outp)[o] = aux1[o] + sg * aux2[o];
                }
            }
        }
    }
}

// ---------- launcher ----------
extern "C" void kernel_launch(void* const* d_in, const int* in_sizes, int n_in,
                              void* d_out, int out_size, void* d_ws, size_t ws_size,
                              hipStream_t stream) {
    const float* x         = (const float*)d_in[0];
    const float* att_shift = (const float*)d_in[1];
    const float* wkv_state = (const float*)d_in[2];
    const float* ffn_shift = (const float*)d_in[3];
    const float* ln1w = (const float*)d_in[4];
    const float* ln1b = (const float*)d_in[5];
    const float* ln2w = (const float*)d_in[6];
    const float* ln2b = (const float*)d_in[7];
    const float* tmk  = (const float*)d_in[8];
    const float* tmv  = (const float*)d_in[9];
    const float* tmr  = (const float*)d_in[10];
    const float* td   = (const float*)d_in[11];
    const float* tf   = (const float*)d_in[12];
    const float* Wk   = (const float*)d_in[13];
    const float* Wv   = (const float*)d_in[14];
    const float* Wr   = (const float*)d_in[15];
    const float* Wo   = (const float*)d_in[16];
    const float* ftmk = (const float*)d_in[17];
    const float* ftmr = (const float*)d_in[18];
    const float* Wfk  = (const float*)d_in[19];   // [F, C]
    const float* Wfv  = (const float*)d_in[20];   // [C, F]
    const float* Wfr  = (const float*)d_in[21];   // [C, C]
    float* out = (float*)d_out;

    char* ws = (char*)d_ws;
    const size_t MB = 1ull << 20;
    float* rx0 = (float*)(ws + 0);            // 16 MB f32 (reduced kv)
    u16*   xk  = (u16*)(ws + 16 * MB);        // 8 MB bf16       (also fk)
    u16*   xv  = (u16*)(ws + 24 * MB);        // 8 MB bf16       (also fr)
    u16*   xr  = (u16*)(ws + 32 * MB);        // 8 MB bf16
    float* kb  = (float*)(ws + 40 * MB);      // 16 MB f32
    float* vb  = (float*)(ws + 56 * MB);      // 16 MB f32
    float* rb  = (float*)(ws + 72 * MB);      // 16 MB f32
    u16*   pb  = (u16*)(ws + 88 * MB);        // 8 MB bf16
    float* x1  = (float*)(ws + 96 * MB);      // 16 MB f32
    u16*   kf  = (u16*)(ws + 112 * MB);       // 32 MB bf16 [T,F]
    u16*   Wb  = (u16*)(ws + 144 * MB);       // 32 MB bf16 weight scratch
    // wkv scratch overlays kf region (dead during TimeMix):
    float* wAb = (float*)(ws + 112 * MB);
    float* wBb = (float*)(ws + 112 * MB + 512 * 1024);
    float* wSa = (float*)(ws + 113 * MB);
    float* wSb = (float*)(ws + 113 * MB + 512 * 1024);
    // ffn_value split-K partials: 2 x 16 MB in [32,64) (xr/kb dead by then)
    float* fvp = (float*)(ws + 32 * MB);

    const int T = T_DIM, C = C_DIM, F = F_DIM;
    const dim3 blk(256);

    // --- TimeMix ---
    ln_mix3<<<T, blk, 0, stream>>>(x, att_shift, ln1w, ln1b, tmk, tmv, tmr, xk, xv, xr);

    // all four CxC weights in one launch: Wb = [Wk|Wv|Wr|Wo]
    cvt4_bf16<<<dim3(1024, 4), blk, 0, stream>>>(Wk, Wv, Wr, Wo, Wb, C * C / 8);
    // batched qkv: grid 16x16x3 = 768 blocks
    gemm_bt<EPI_F32><<<dim3(C / 128, T / 128, 3), blk, 0, stream>>>(
        xk, C, (long)T * C, Wb, C, (long)C * C, 0, C,
        kb, C, (long)T * C, nullptr, nullptr);

    wkv_part<<<(C * WKV_P) / 256, blk, 0, stream>>>(td, kb, vb, wAb, wBb);
    wkv_comb<<<C / 256, blk, 0, stream>>>(td, wkv_state, wAb, wBb, wSa, wSb);
    wkv_emit<<<(C * WKV_P) / 256, blk, 0, stream>>>(td, tf, kb, vb, rb, wSa, wSb, pb);

    // att_out fused +x: 256 blocks (Wo already converted at Wb+3*C*C)
    gemm_bt<EPI_ADDX><<<dim3(C / 128, T / 128, 1), blk, 0, stream>>>(
        pb, C, 0, Wb + 3 * (size_t)C * C, C, 0, 0, C, x1, C, 0, x, nullptr);

    // --- ChannelMix ---
    ln_mix2<<<T, blk, 0, stream>>>(x1, ffn_shift, ln2w, ln2b, ftmk, ftmr, xk, xv);

    cvt_bf16<<<2048, blk, 0, stream>>>(Wfk, Wb, F * C / 8);
    // ffn_key: grid 64x16 = 1024 blocks
    gemm_bt<EPI_RELU2><<<dim3(F / 128, T / 128, 1), blk, 0, stream>>>(
        xk, C, 0, Wb, C, 0, 0, C, kf, F, 0, nullptr, nullptr);

    cvt_bf16<<<2048, blk, 0, stream>>>(Wfv, Wb, C * F / 8);
    // ffn_value split-K x2 over K=8192: 512 blocks, koff=4096
    gemm_bt<EPI_F32><<<dim3(C / 128, T / 128, 2), blk, 0, stream>>>(
        kf, F, 0, Wb, F, 0, 4096, 4096, fvp, C, (long)T * C, nullptr, nullptr);
    reduce2<<<2048, blk, 0, stream>>>(fvp, fvp + (size_t)T * C, rx0, T * C / 4);

    cvt_bf16<<<2048, blk, 0, stream>>>(Wfr, Wb, C * C / 8);
    // ffn_recept fused sigmoid*kv+x1: 256 blocks
    gemm_bt<EPI_SIGMULADD><<<dim3(C / 128, T / 128, 1), blk, 0, stream>>>(
        xv, C, 0, Wb, C, 0, 0, C, out, C, 0, x1, rx0);
}

// Round 10
// 388.114 us; speedup vs baseline: 1.0623x; 1.0623x over previous
//
#include <hip/hip_runtime.h>
#include <hip/hip_bf16.h>

typedef unsigned short u16;
typedef short bf16x8 __attribute__((ext_vector_type(8)));
typedef float f32x4 __attribute__((ext_vector_type(4)));

#define T_DIM 2048
#define C_DIM 2048
#define F_DIM 8192
#define WKV_L 32
#define WKV_P (T_DIM / WKV_L)   // 64 chunks

// ---------- helpers ----------
__device__ __forceinline__ u16 f2bf(float f) {
    unsigned int u = __float_as_uint(f);
    u += 0x7fff + ((u >> 16) & 1);          // round-to-nearest-even
    return (u16)(u >> 16);
}

__device__ __forceinline__ void async16(const void* g, void* l) {
    __builtin_amdgcn_global_load_lds(
        (__attribute__((address_space(1))) const unsigned int*)g,
        (__attribute__((address_space(3))) unsigned int*)l, 16, 0, 0);
}

// ---------- fused LayerNorm + token-shift mix (3 outputs) ----------
__global__ __launch_bounds__(256) void ln_mix3(
        const float* __restrict__ x, const float* __restrict__ sh,
        const float* __restrict__ w, const float* __restrict__ b,
        const float* __restrict__ mk, const float* __restrict__ mv,
        const float* __restrict__ mr,
        u16* __restrict__ xk, u16* __restrict__ xv, u16* __restrict__ xr) {
    __shared__ float red[16];
    const int t = blockIdx.x, tid = threadIdx.x;
    const float4* cr = (const float4*)(x + (size_t)t * C_DIM);
    float4 c0 = cr[tid * 2], c1 = cr[tid * 2 + 1];
    float s = c0.x + c0.y + c0.z + c0.w + c1.x + c1.y + c1.z + c1.w;
    float q = c0.x * c0.x + c0.y * c0.y + c0.z * c0.z + c0.w * c0.w
            + c1.x * c1.x + c1.y * c1.y + c1.z * c1.z + c1.w * c1.w;
    float4 p0, p1;
    float sp = 0.f, qp = 0.f;
    if (t > 0) {
        const float4* pr = (const float4*)(x + (size_t)(t - 1) * C_DIM);
        p0 = pr[tid * 2]; p1 = pr[tid * 2 + 1];
        sp = p0.x + p0.y + p0.z + p0.w + p1.x + p1.y + p1.z + p1.w;
        qp = p0.x * p0.x + p0.y * p0.y + p0.z * p0.z + p0.w * p0.w
           + p1.x * p1.x + p1.y * p1.y + p1.z * p1.z + p1.w * p1.w;
    } else {
        const float4* pr = (const float4*)sh;
        p0 = pr[tid * 2]; p1 = pr[tid * 2 + 1];
    }
    #pragma unroll
    for (int off = 32; off > 0; off >>= 1) {
        s += __shfl_down(s, off);   q += __shfl_down(q, off);
        sp += __shfl_down(sp, off); qp += __shfl_down(qp, off);
    }
    const int lane = tid & 63, wv = tid >> 6;
    if (lane == 0) { red[wv] = s; red[4 + wv] = q; red[8 + wv] = sp; red[12 + wv] = qp; }
    __syncthreads();
    if (tid == 0) {
        red[0] += red[1] + red[2] + red[3];
        red[4] += red[5] + red[6] + red[7];
        red[8] += red[9] + red[10] + red[11];
        red[12] += red[13] + red[14] + red[15];
    }
    __syncthreads();
    const float mc = red[0] * (1.f / C_DIM);
    const float ic = rsqrtf(red[4] * (1.f / C_DIM) - mc * mc + 1e-5f);
    const float mp = red[8] * (1.f / C_DIM);
    const float ip = rsqrtf(red[12] * (1.f / C_DIM) - mp * mp + 1e-5f);
    const float4* w4 = (const float4*)w;
    const float4* b4 = (const float4*)b;
    #pragma unroll
    for (int j = 0; j < 2; ++j) {
        const int i4 = tid * 2 + j;
        float4 cv = j ? c1 : c0, pv = j ? p1 : p0;
        float4 wv4 = w4[i4], bv = b4[i4];
        float4 cl, pl;
        cl.x = (cv.x - mc) * ic * wv4.x + bv.x;
        cl.y = (cv.y - mc) * ic * wv4.y + bv.y;
        cl.z = (cv.z - mc) * ic * wv4.z + bv.z;
        cl.w = (cv.w - mc) * ic * wv4.w + bv.w;
        if (t > 0) {
            pl.x = (pv.x - mp) * ip * wv4.x + bv.x;
            pl.y = (pv.y - mp) * ip * wv4.y + bv.y;
            pl.z = (pv.z - mp) * ip * wv4.z + bv.z;
            pl.w = (pv.w - mp) * ip * wv4.w + bv.w;
        } else pl = pv;
        const size_t o = (size_t)t * (C_DIM / 4) + i4;
        float4 m;
        ushort4 r;
        m = ((const float4*)mk)[i4];
        r.x = f2bf(cl.x * m.x + pl.x * (1.f - m.x));
        r.y = f2bf(cl.y * m.y + pl.y * (1.f - m.y));
        r.z = f2bf(cl.z * m.z + pl.z * (1.f - m.z));
        r.w = f2bf(cl.w * m.w + pl.w * (1.f - m.w));
        ((ushort4*)xk)[o] = r;
        m = ((const float4*)mv)[i4];
        r.x = f2bf(cl.x * m.x + pl.x * (1.f - m.x));
        r.y = f2bf(cl.y * m.y + pl.y * (1.f - m.y));
        r.z = f2bf(cl.z * m.z + pl.z * (1.f - m.z));
        r.w = f2bf(cl.w * m.w + pl.w * (1.f - m.w));
        ((ushort4*)xv)[o] = r;
        m = ((const float4*)mr)[i4];
        r.x = f2bf(cl.x * m.x + pl.x * (1.f - m.x));
        r.y = f2bf(cl.y * m.y + pl.y * (1.f - m.y));
        r.z = f2bf(cl.z * m.z + pl.z * (1.f - m.z));
        r.w = f2bf(cl.w * m.w + pl.w * (1.f - m.w));
        ((ushort4*)xr)[o] = r;
    }
}

// ---------- fused LayerNorm + token-shift mix (2 outputs) ----------
__global__ __launch_bounds__(256) void ln_mix2(
        const float* __restrict__ x, const float* __restrict__ sh,
        const float* __restrict__ w, const float* __restrict__ b,
        const float* __restrict__ mk, const float* __restrict__ mr,
        u16* __restrict__ fk, u16* __restrict__ fr) {
    __shared__ float red[16];
    const int t = blockIdx.x, tid = threadIdx.x;
    const float4* cr = (const float4*)(x + (size_t)t * C_DIM);
    float4 c0 = cr[tid * 2], c1 = cr[tid * 2 + 1];
    float s = c0.x + c0.y + c0.z + c0.w + c1.x + c1.y + c1.z + c1.w;
    float q = c0.x * c0.x + c0.y * c0.y + c0.z * c0.z + c0.w * c0.w
            + c1.x * c1.x + c1.y * c1.y + c1.z * c1.z + c1.w * c1.w;
    float4 p0, p1;
    float sp = 0.f, qp = 0.f;
    if (t > 0) {
        const float4* pr = (const float4*)(x + (size_t)(t - 1) * C_DIM);
        p0 = pr[tid * 2]; p1 = pr[tid * 2 + 1];
        sp = p0.x + p0.y + p0.z + p0.w + p1.x + p1.y + p1.z + p1.w;
        qp = p0.x * p0.x + p0.y * p0.y + p0.z * p0.z + p0.w * p0.w
           + p1.x * p1.x + p1.y * p1.y + p1.z * p1.z + p1.w * p1.w;
    } else {
        const float4* pr = (const float4*)sh;
        p0 = pr[tid * 2]; p1 = pr[tid * 2 + 1];
    }
    #pragma unroll
    for (int off = 32; off > 0; off >>= 1) {
        s += __shfl_down(s, off);   q += __shfl_down(q, off);
        sp += __shfl_down(sp, off); qp += __shfl_down(qp, off);
    }
    const int lane = tid & 63, wv = tid >> 6;
    if (lane == 0) { red[wv] = s; red[4 + wv] = q; red[8 + wv] = sp; red[12 + wv] = qp; }
    __syncthreads();
    if (tid == 0) {
        red[0] += red[1] + red[2] + red[3];
        red[4] += red[5] + red[6] + red[7];
        red[8] += red[9] + red[10] + red[11];
        red[12] += red[13] + red[14] + red[15];
    }
    __syncthreads();
    const float mc = red[0] * (1.f / C_DIM);
    const float ic = rsqrtf(red[4] * (1.f / C_DIM) - mc * mc + 1e-5f);
    const float mp = red[8] * (1.f / C_DIM);
    const float ip = rsqrtf(red[12] * (1.f / C_DIM) - mp * mp + 1e-5f);
    const float4* w4 = (const float4*)w;
    const float4* b4 = (const float4*)b;
    #pragma unroll
    for (int j = 0; j < 2; ++j) {
        const int i4 = tid * 2 + j;
        float4 cv = j ? c1 : c0, pv = j ? p1 : p0;
        float4 wv4 = w4[i4], bv = b4[i4];
        float4 cl, pl;
        cl.x = (cv.x - mc) * ic * wv4.x + bv.x;
        cl.y = (cv.y - mc) * ic * wv4.y + bv.y;
        cl.z = (cv.z - mc) * ic * wv4.z + bv.z;
        cl.w = (cv.w - mc) * ic * wv4.w + bv.w;
        if (t > 0) {
            pl.x = (pv.x - mp) * ip * wv4.x + bv.x;
            pl.y = (pv.y - mp) * ip * wv4.y + bv.y;
            pl.z = (pv.z - mp) * ip * wv4.z + bv.z;
            pl.w = (pv.w - mp) * ip * wv4.w + bv.w;
        } else pl = pv;
        const size_t o = (size_t)t * (C_DIM / 4) + i4;
        float4 m;
        ushort4 r;
        m = ((const float4*)mk)[i4];
        r.x = f2bf(cl.x * m.x + pl.x * (1.f - m.x));
        r.y = f2bf(cl.y * m.y + pl.y * (1.f - m.y));
        r.z = f2bf(cl.z * m.z + pl.z * (1.f - m.z));
        r.w = f2bf(cl.w * m.w + pl.w * (1.f - m.w));
        ((ushort4*)fk)[o] = r;
        m = ((const float4*)mr)[i4];
        r.x = f2bf(cl.x * m.x + pl.x * (1.f - m.x));
        r.y = f2bf(cl.y * m.y + pl.y * (1.f - m.y));
        r.z = f2bf(cl.z * m.z + pl.z * (1.f - m.z));
        r.w = f2bf(cl.w * m.w + pl.w * (1.f - m.w));
        ((ushort4*)fr)[o] = r;
    }
}

// ---------- f32 -> bf16 conversion ----------
__global__ __launch_bounds__(256) void cvt_bf16(const float* __restrict__ in,
                                                u16* __restrict__ out, int n8) {
    int i = blockIdx.x * 256 + threadIdx.x;
    const int stride = gridDim.x * 256;
    for (; i < n8; i += stride) {
        const float4* p = (const float4*)(in + (size_t)i * 8);
        float4 a = p[0], b = p[1];
        ushort4 lo, hi;
        lo.x = f2bf(a.x); lo.y = f2bf(a.y); lo.z = f2bf(a.z); lo.w = f2bf(a.w);
        hi.x = f2bf(b.x); hi.y = f2bf(b.y); hi.z = f2bf(b.z); hi.w = f2bf(b.w);
        ((ushort4*)out)[i * 2] = lo;
        ((ushort4*)out)[i * 2 + 1] = hi;
    }
}

// four C*C weights in one launch (blockIdx.y selects the array)
__global__ __launch_bounds__(256) void cvt4_bf16(const float* __restrict__ i0,
                                                 const float* __restrict__ i1,
                                                 const float* __restrict__ i2,
                                                 const float* __restrict__ i3,
                                                 u16* __restrict__ out, int n8) {
    const int sel = blockIdx.y;
    const float* in = sel == 0 ? i0 : (sel == 1 ? i1 : (sel == 2 ? i2 : i3));
    u16* o = out + (size_t)sel * n8 * 8;
    int i = blockIdx.x * 256 + threadIdx.x;
    const int stride = gridDim.x * 256;
    for (; i < n8; i += stride) {
        const float4* p = (const float4*)(in + (size_t)i * 8);
        float4 a = p[0], b = p[1];
        ushort4 lo, hi;
        lo.x = f2bf(a.x); lo.y = f2bf(a.y); lo.z = f2bf(a.z); lo.w = f2bf(a.w);
        hi.x = f2bf(b.x); hi.y = f2bf(b.y); hi.z = f2bf(b.z); hi.w = f2bf(b.w);
        ((ushort4*)o)[i * 2] = lo;
        ((ushort4*)o)[i * 2 + 1] = hi;
    }
}

// ---------- 4-way partial-sum reduce (float4) ----------
__global__ __launch_bounds__(256) void reduce4(const float* __restrict__ p0,
                                               const float* __restrict__ p1,
                                               const float* __restrict__ p2,
                                               const float* __restrict__ p3,
                                               float* __restrict__ o, int n4) {
    int i = blockIdx.x * 256 + threadIdx.x;
    const int stride = gridDim.x * 256;
    for (; i < n4; i += stride) {
        float4 a = ((const float4*)p0)[i], b = ((const float4*)p1)[i];
        float4 c = ((const float4*)p2)[i], d = ((const float4*)p3)[i];
        float4 r;
        r.x = a.x + b.x + c.x + d.x;
        r.y = a.y + b.y + c.y + d.y;
        r.z = a.z + b.z + c.z + d.z;
        r.w = a.w + b.w + c.w + d.w;
        ((float4*)o)[i] = r;
    }
}

// ---------- WKV parallel scan ----------
__global__ __launch_bounds__(256) void wkv_part(const float* __restrict__ td,
                                                const float* __restrict__ k,
                                                const float* __restrict__ v,
                                                float* __restrict__ Ab,
                                                float* __restrict__ Bb) {
    const int idx = blockIdx.x * 256 + threadIdx.x;     // C*P threads
    const int c = idx & (C_DIM - 1);
    const int p = idx >> 11;
    const float ew = expf(-expf(td[c]));
    float A = 0.f, B = 0.f;
    size_t o = (size_t)(p * WKV_L) * C_DIM + c;
    #pragma unroll 4
    for (int i = 0; i < WKV_L; ++i, o += C_DIM) {
        const float kk = expf(k[o]);
        A = (A + kk * v[o]) * ew;
        B = (B + kk) * ew;
    }
    Ab[p * C_DIM + c] = A;
    Bb[p * C_DIM + c] = B;
}

__global__ __launch_bounds__(256) void wkv_comb(const float* __restrict__ td,
                                                const float* __restrict__ st,
                                                const float* __restrict__ Ab,
                                                const float* __restrict__ Bb,
                                                float* __restrict__ Sa,
                                                float* __restrict__ Sb) {
    const int c = blockIdx.x * 256 + threadIdx.x;       // C threads
    const float w = -expf(td[c]);
    const float dL = expf(w * (float)WKV_L);            // ew^L
    float a = st[c];
    float b = st[C_DIM + c];
    #pragma unroll 4
    for (int p = 0; p < WKV_P; ++p) {
        Sa[p * C_DIM + c] = a;
        Sb[p * C_DIM + c] = b;
        a = dL * a + Ab[p * C_DIM + c];
        b = dL * b + Bb[p * C_DIM + c];
    }
}

__global__ __launch_bounds__(256) void wkv_emit(const float* __restrict__ td,
                                                const float* __restrict__ tf,
                                                const float* __restrict__ k,
                                                const float* __restrict__ v,
                                                const float* __restrict__ r,
                                                const float* __restrict__ Sa,
                                                const float* __restrict__ Sb,
                                                u16* __restrict__ pout) {
    const int idx = blockIdx.x * 256 + threadIdx.x;     // C*P threads
    const int c = idx & (C_DIM - 1);
    const int p = idx >> 11;
    const float u = tf[c];
    const float w = -expf(td[c]);
    const float ew = expf(w);
    float a = Sa[p * C_DIM + c];
    float b = Sb[p * C_DIM + c];
    size_t o = (size_t)(p * WKV_L) * C_DIM + c;
    #pragma unroll 2
    for (int i = 0; i < WKV_L; ++i, o += C_DIM) {
        const float kt = k[o], vt = v[o], rt = r[o];
        const float e = expf(u + w + kt);
        const float y = (a + e * vt) / (b + e);
        const float kk = expf(kt);
        a = (a + kk * vt) * ew;
        b = (b + kk) * ew;
        const float sr = 1.f / (1.f + expf(-rt));
        pout[o] = f2bf(sr * y);
    }
}

enum { EPI_F32 = 0, EPI_ADDX = 1, EPI_RELU2 = 2, EPI_SIGMULADD = 3 };

// ---------- 128x128 bf16 NT GEMM — 3-slot pipeline (R9, proven) ----------
template <int EPI>
__global__ __launch_bounds__(256, 3) void gemm_bt(
        const u16* __restrict__ A, int lda, long a_zs,
        const u16* __restrict__ B, int ldb, long b_zs,
        long koff, int Kloop,
        void* __restrict__ outp, int ldo, long o_zs,
        const float* __restrict__ aux1, const float* __restrict__ aux2) {
    __shared__ u16 lds[3 * 8192];   // 48 KiB: 3 slots x (A 8KB + B 8KB)
    const int tid = threadIdx.x;
    const int l = tid & 63, w = tid >> 6;
    const int wr2 = w >> 1, wc2 = w & 1;     // 2x2 waves of 64x64

    const int gx = gridDim.x, gy = gridDim.y;
    const int nxy = gx * gy;
    const int flat = (blockIdx.z * gy + blockIdx.y) * gx + blockIdx.x;
    const int cpx = (nxy * gridDim.z) >> 3;
    const int swz = (flat & 7) * cpx + (flat >> 3);
    const int z = swz / nxy;
    const int rem = swz - z * nxy;
    const int bm = rem % gy;
    const int bn = rem / gy;

    const u16* Ag = A + (size_t)z * a_zs + (size_t)z * koff + (size_t)bm * 128 * lda;
    const u16* Bg = B + (size_t)z * b_zs + (size_t)z * koff + (size_t)bn * 128 * ldb;

    long gA[2], gB[2];
    int dA[2], dB[2];
    #pragma unroll
    for (int j = 0; j < 2; ++j) {
        const int off = j * 4096 + w * 1024 + l * 16;
        const int row = off >> 6;
        const int cb = (off & 63) ^ (((off >> 9) & 1) << 5);
        gA[j] = (long)row * lda + (cb >> 1);
        gB[j] = (long)row * ldb + (cb >> 1);
        dA[j] = j * 2048 + w * 512;
        dB[j] = 4096 + j * 2048 + w * 512;
    }

    int offA[4], offB[4];
    #pragma unroll
    for (int m = 0; m < 4; ++m) {
        const int lin = (wr2 * 64 + m * 16 + (l & 15)) * 64 + ((l >> 4) << 4);
        offA[m] = (lin ^ (((lin >> 9) & 1) << 5)) >> 1;
    }
    #pragma unroll
    for (int n = 0; n < 4; ++n) {
        const int lin = (wc2 * 64 + n * 16 + (l & 15)) * 64 + ((l >> 4) << 4);
        offB[n] = 4096 + ((lin ^ (((lin >> 9) & 1) << 5)) >> 1);
    }

    const f32x4 fz = {0.f, 0.f, 0.f, 0.f};
    f32x4 acc[4][4];
    #pragma unroll
    for (int m = 0; m < 4; ++m)
        #pragma unroll
        for (int n = 0; n < 4; ++n) acc[m][n] = fz;

    const int NT = Kloop >> 5;

    auto stage = [&](int kt, int sp) {
        const long ko = (long)kt << 5;
        const int sb = sp * 8192;
        async16(Ag + gA[0] + ko, &lds[sb + dA[0]]);
        async16(Ag + gA[1] + ko, &lds[sb + dA[1]]);
        async16(Bg + gB[0] + ko, &lds[sb + dB[0]]);
        async16(Bg + gB[1] + ko, &lds[sb + dB[1]]);
    };

    stage(0, 0);
    stage(1, 1);

    int sr = 0;
    for (int t = 0; t < NT; ++t) {
        asm volatile("s_waitcnt vmcnt(4)" ::: "memory");
        __builtin_amdgcn_s_barrier();
        __builtin_amdgcn_sched_barrier(0);
        {
            const int tp = (t + 2 < NT) ? t + 2 : NT - 1;
            const int sp = (sr == 0) ? 2 : sr - 1;
            stage(tp, sp);
        }
        const int sb = sr * 8192;
        bf16x8 af[4], bfv[4];
        #pragma unroll
        for (int m = 0; m < 4; ++m) af[m] = *(const bf16x8*)&lds[sb + offA[m]];
        #pragma unroll
        for (int n = 0; n < 4; ++n) bfv[n] = *(const bf16x8*)&lds[sb + offB[n]];
        __builtin_amdgcn_s_setprio(1);
        #pragma unroll
        for (int m = 0; m < 2; ++m)
            #pragma unroll
            for (int n = 0; n < 4; ++n)
                acc[m][n] = __builtin_amdgcn_mfma_f32_16x16x32_bf16(af[m], bfv[n], acc[m][n], 0, 0, 0);
        __builtin_amdgcn_s_setprio(0);
        __builtin_amdgcn_s_setprio(1);
        #pragma unroll
        for (int m = 2; m < 4; ++m)
            #pragma unroll
            for (int n = 0; n < 4; ++n)
                acc[m][n] = __builtin_amdgcn_mfma_f32_16x16x32_bf16(af[m], bfv[n], acc[m][n], 0, 0, 0);
        __builtin_amdgcn_s_setprio(0);
        sr = (sr == 2) ? 0 : sr + 1;
    }
    asm volatile("s_waitcnt vmcnt(0)" ::: "memory");

    const int r00 = bm * 128 + wr2 * 64 + ((l >> 4) << 2);
    const int c00 = bn * 128 + wc2 * 64 + (l & 15);
    #pragma unroll
    for (int m = 0; m < 4; ++m) {
        #pragma unroll
        for (int n = 0; n < 4; ++n) {
            #pragma unroll
            for (int j = 0; j < 4; ++j) {
                const int rr = r00 + m * 16 + j;
                const int cc = c00 + n * 16;
                const size_t o = (size_t)rr * ldo + cc;
                const float val = acc[m][n][j];
                if constexpr (EPI == EPI_F32) {
                    ((float*)outp)[(size_t)z * o_zs + o] = val;
                } else if constexpr (EPI == EPI_ADDX) {
                    ((float*)outp)[o] = aux1[o] + val;
                } else if constexpr (EPI == EPI_RELU2) {
                    const float tp2 = fmaxf(val, 0.f);
                    ((u16*)outp)[o] = f2bf(tp2 * tp2);
                } else {  // EPI_SIGMULADD
                    const float sg = 1.f / (1.f + expf(-val));
                    ((float*)outp)[o] = aux1[o] + sg * aux2[o];
                }
            }
        }
    }
}

// ---------- 256x256 bf16 NT GEMM — m201-style 8-phase, counted vmcnt ------
// BM=BN=256, BK=64, 512 thr = 8 waves (2M x 4N; per-wave 128x64 out).
// LDS 128 KiB = 2 buffers x (A 32KB + B 32KB); 128B rows, bit9->bit5 XOR
// swizzle (pre-swizzled global source, swizzled ds_read).
// Per K-tile: 4 phases {ds_read 8/8/8/0 | stage 1 half (2 loads) | barrier |
// lgkm0+sched_barrier | setprio 16-MFMA quadrant | barrier}.
// Stagger: [ph3..ph6] stage buf0<-kt+2; [ph7,ph0',ph1',ph2'] stage buf1<-kt+3.
// Safety: buffer reads all ISSUED by its 3rd phase, completed at that phase's
// lgkm0 (before MFMA, before closing barrier) => 4th-phase staging is safe.
// vmcnt(2) ONLY at phases 4 & 8 (1 half in flight) — never drained in-loop.
template <int EPI>
__global__ __launch_bounds__(512, 2) void gemm8p(
        const u16* __restrict__ A, int lda,
        const u16* __restrict__ B, int ldb,
        long koff, int Kloop,
        void* __restrict__ outp, int ldo, long o_zs) {
    __shared__ u16 lds[65536];   // 128 KiB
    const int tid = threadIdx.x;
    const int l = tid & 63, w = tid >> 6;
    const int wm = w >> 2, wn = w & 3;

    const int gx = gridDim.x, gy = gridDim.y;
    const int nxy = gx * gy;
    const int flat = (blockIdx.z * gy + blockIdx.y) * gx + blockIdx.x;
    const int cpx = (nxy * gridDim.z) >> 3;
    const int swz = (flat & 7) * cpx + (flat >> 3);
    const int z = swz / nxy;
    const int rem = swz - z * nxy;
    const int bm = rem % gy;
    const int bn = rem / gy;

    const u16* Ag = A + (size_t)z * koff + (size_t)bm * 256 * lda;
    const u16* Bg = B + (size_t)z * koff + (size_t)bn * 256 * ldb;

    // staging: linear LDS dest, pre-swizzled global source. halves h, loads j.
    long srcA[4], srcB[4];
    int dst[4];
    #pragma unroll
    for (int hj = 0; hj < 4; ++hj) {
        const int off = (hj >> 1) * 16384 + (hj & 1) * 8192 + w * 1024 + l * 16;
        const int e = off ^ (((off >> 9) & 1) << 5);
        srcA[hj] = (long)(e >> 7) * lda + ((e & 127) >> 1);
        srcB[hj] = (long)(e >> 7) * ldb + ((e & 127) >> 1);
        dst[hj] = off >> 1;              // local elem index within region
    }

    // ds_read offsets at ks=0 (ks=1 adds +32 elems: +64 bytes, bit9-safe)
    int offA[2][4], offB0[4];
    #pragma unroll
    for (int mh = 0; mh < 2; ++mh)
        #pragma unroll
        for (int mi = 0; mi < 4; ++mi) {
            const int row = wm * 128 + (mh * 4 + mi) * 16 + (l & 15);
            const int lin = row * 128 + ((l >> 4) << 4);
            offA[mh][mi] = (lin ^ (((lin >> 9) & 1) << 5)) >> 1;
        }
    #pragma unroll
    for (int n = 0; n < 4; ++n) {
        const int row = wn * 64 + n * 16 + (l & 15);
        const int lin = row * 128 + ((l >> 4) << 4);
        offB0[n] = 16384 + ((lin ^ (((lin >> 9) & 1) << 5)) >> 1);
    }

    const f32x4 fz = {0.f, 0.f, 0.f, 0.f};
    f32x4 acc[8][4];
    #pragma unroll
    for (int m = 0; m < 8; ++m)
        #pragma unroll
        for (int n = 0; n < 4; ++n) acc[m][n] = fz;

    const int NT = Kloop >> 6;          // K-tiles of 64
    const int NP = NT >> 1;             // buffer pairs

    auto stgA = [&](int kt, int buf, int h) {
        const long ko = (long)kt << 6;
        #pragma unroll
        for (int j = 0; j < 2; ++j)
            async16(Ag + srcA[h * 2 + j] + ko, &lds[buf * 32768 + dst[h * 2 + j]]);
    };
    auto stgB = [&](int kt, int buf, int h) {
        const long ko = (long)kt << 6;
        #pragma unroll
        for (int j = 0; j < 2; ++j)
            async16(Bg + srcB[h * 2 + j] + ko, &lds[buf * 32768 + 16384 + dst[h * 2 + j]]);
    };

#define PH_OPEN() __builtin_amdgcn_s_barrier(); \
    asm volatile("s_waitcnt lgkmcnt(0)" ::: "memory"); \
    __builtin_amdgcn_sched_barrier(0)
#define QUAD(af, bf, MO) \
    __builtin_amdgcn_s_setprio(1); \
    _Pragma("unroll") \
    for (int mi = 0; mi < 4; ++mi) \
        _Pragma("unroll") \
        for (int n = 0; n < 4; ++n) \
            acc[MO + mi][n] = __builtin_amdgcn_mfma_f32_16x16x32_bf16((af)[mi], (bf)[n], acc[MO + mi][n], 0, 0, 0); \
    __builtin_amdgcn_s_setprio(0)

    // prologue: buf0 <- kt0 (4 halves), buf1 <- kt1 A-half0. 10 loads.
    stgA(0, 0, 0); stgA(0, 0, 1); stgB(0, 0, 0); stgB(0, 0, 1);
    stgA(1, 1, 0);
    asm volatile("s_waitcnt vmcnt(2)" ::: "memory");   // buf0 landed
    __builtin_amdgcn_s_barrier();

    for (int p = 0; p < NP; ++p) {
        const int kt1 = 2 * p + 1;
        const int kn0 = (2 * p + 2 < NT) ? 2 * p + 2 : NT - 1;  // clamped tail
        const int kn1 = (2 * p + 3 < NT) ? 2 * p + 3 : NT - 1;
        bf16x8 a0[4], a1[4], a0k[4], a1k[4], bb[4];
        // ===== buf0 (kt=2p) =====
        // ph0: reads A-mh0-ks0 + B-ks0; stage buf1.A-h1 (kt1)
        #pragma unroll
        for (int mi = 0; mi < 4; ++mi) a0[mi] = *(const bf16x8*)&lds[offA[0][mi]];
        #pragma unroll
        for (int n = 0; n < 4; ++n) bb[n] = *(const bf16x8*)&lds[offB0[n]];
        stgA(kt1, 1, 1);
        PH_OPEN(); QUAD(a0, bb, 0);
        __builtin_amdgcn_s_barrier();
        // ph1: reads A-mh1-ks0 + A-mh0-ks1; stage buf1.B-h0 (kt1)
        #pragma unroll
        for (int mi = 0; mi < 4; ++mi) a1[mi] = *(const bf16x8*)&lds[offA[1][mi]];
        #pragma unroll
        for (int mi = 0; mi < 4; ++mi) a0k[mi] = *(const bf16x8*)&lds[offA[0][mi] + 32];
        stgB(kt1, 1, 0);
        PH_OPEN(); QUAD(a1, bb, 4);
        __builtin_amdgcn_s_barrier();
        // ph2: reads B-ks1 + A-mh1-ks1; stage buf1.B-h1 (kt1)
        #pragma unroll
        for (int n = 0; n < 4; ++n) bb[n] = *(const bf16x8*)&lds[offB0[n] + 32];
        #pragma unroll
        for (int mi = 0; mi < 4; ++mi) a1k[mi] = *(const bf16x8*)&lds[offA[1][mi] + 32];
        stgB(kt1, 1, 1);
        PH_OPEN(); QUAD(a0k, bb, 0);
        __builtin_amdgcn_s_barrier();
        // ph3: no reads; stage buf0.A-h0 (kn0); checkpoint vmcnt(2)
        stgA(kn0, 0, 0);
        PH_OPEN(); QUAD(a1k, bb, 4);
        asm volatile("s_waitcnt vmcnt(2)" ::: "memory");  // buf1 (kt1) landed
        __builtin_amdgcn_s_barrier();
        // ===== buf1 (kt=2p+1) =====
        // ph4
        #pragma unroll
        for (int mi = 0; mi < 4; ++mi) a0[mi] = *(const bf16x8*)&lds[32768 + offA[0][mi]];
        #pragma unroll
        for (int n = 0; n < 4; ++n) bb[n] = *(const bf16x8*)&lds[32768 + offB0[n]];
        stgA(kn0, 0, 1);
        PH_OPEN(); QUAD(a0, bb, 0);
        __builtin_amdgcn_s_barrier();
        // ph5
        #pragma unroll
        for (int mi = 0; mi < 4; ++mi) a1[mi] = *(const bf16x8*)&lds[32768 + offA[1][mi]];
        #pragma unroll
        for (int mi = 0; mi < 4; ++mi) a0k[mi] = *(const bf16x8*)&lds[32768 + offA[0][mi] + 32];
        stgB(kn0, 0, 0);
        PH_OPEN(); QUAD(a1, bb, 4);
        __builtin_amdgcn_s_barrier();
        // ph6
        #pragma unroll
        for (int n = 0; n < 4; ++n) bb[n] = *(const bf16x8*)&lds[32768 + offB0[n] + 32];
        #pragma unroll
        for (int mi = 0; mi < 4; ++mi) a1k[mi] = *(const bf16x8*)&lds[32768 + offA[1][mi] + 32];
        stgB(kn0, 0, 1);
        PH_OPEN(); QUAD(a0k, bb, 0);
        __builtin_amdgcn_s_barrier();
        // ph7: stage buf1.A-h0 (kn1); checkpoint vmcnt(2)
        stgA(kn1, 1, 0);
        PH_OPEN(); QUAD(a1k, bb, 4);
        asm volatile("s_waitcnt vmcnt(2)" ::: "memory");  // buf0 (kn0) landed
        __builtin_amdgcn_s_barrier();
    }
    asm volatile("s_waitcnt vmcnt(0)" ::: "memory");  // drain clamped tail

#undef PH_OPEN
#undef QUAD

    // --- epilogue (verified 256²/8-wave mapping) ---
    const int r00 = bm * 256 + wm * 128 + ((l >> 4) << 2);
    const int c00 = bn * 256 + wn * 64 + (l & 15);
    #pragma unroll
    for (int m = 0; m < 8; ++m) {
        #pragma unroll
        for (int n = 0; n < 4; ++n) {
            #pragma unroll
            for (int j = 0; j < 4; ++j) {
                const int rr = r00 + m * 16 + j;
                const int cc = c00 + n * 16;
                const size_t o = (size_t)rr * ldo + cc;
                const float val = acc[m][n][j];
                if constexpr (EPI == EPI_F32) {
                    ((float*)outp)[(size_t)z * o_zs + o] = val;
                } else {  // EPI_RELU2
                    const float tp2 = fmaxf(val, 0.f);
                    ((u16*)outp)[o] = f2bf(tp2 * tp2);
                }
            }
        }
    }
}

// ---------- launcher ----------
extern "C" void kernel_launch(void* const* d_in, const int* in_sizes, int n_in,
                              void* d_out, int out_size, void* d_ws, size_t ws_size,
                              hipStream_t stream) {
    const float* x         = (const float*)d_in[0];
    const float* att_shift = (const float*)d_in[1];
    const float* wkv_state = (const float*)d_in[2];
    const float* ffn_shift = (const float*)d_in[3];
    const float* ln1w = (const float*)d_in[4];
    const float* ln1b = (const float*)d_in[5];
    const float* ln2w = (const float*)d_in[6];
    const float* ln2b = (const float*)d_in[7];
    const float* tmk  = (const float*)d_in[8];
    const float* tmv  = (const float*)d_in[9];
    const float* tmr  = (const float*)d_in[10];
    const float* td   = (const float*)d_in[11];
    const float* tf   = (const float*)d_in[12];
    const float* Wk   = (const float*)d_in[13];
    const float* Wv   = (const float*)d_in[14];
    const float* Wr   = (const float*)d_in[15];
    const float* Wo   = (const float*)d_in[16];
    const float* ftmk = (const float*)d_in[17];
    const float* ftmr = (const float*)d_in[18];
    const float* Wfk  = (const float*)d_in[19];   // [F, C]
    const float* Wfv  = (const float*)d_in[20];   // [C, F]
    const float* Wfr  = (const float*)d_in[21];   // [C, C]
    float* out = (float*)d_out;

    char* ws = (char*)d_ws;
    const size_t MB = 1ull << 20;
    float* rx0 = (float*)(ws + 0);            // 16 MB f32 (reduced kv)
    u16*   xk  = (u16*)(ws + 16 * MB);        // 8 MB bf16       (also fk)
    u16*   xv  = (u16*)(ws + 24 * MB);        // 8 MB bf16       (also fr)
    u16*   xr  = (u16*)(ws + 32 * MB);        // 8 MB bf16
    float* kb  = (float*)(ws + 40 * MB);      // 16 MB f32
    float* vb  = (float*)(ws + 56 * MB);      // 16 MB f32
    float* rb  = (float*)(ws + 72 * MB);      // 16 MB f32
    u16*   pb  = (u16*)(ws + 88 * MB);        // 8 MB bf16
    float* x1  = (float*)(ws + 96 * MB);      // 16 MB f32
    u16*   kf  = (u16*)(ws + 112 * MB);       // 32 MB bf16 [T,F]
    u16*   Wb  = (u16*)(ws + 144 * MB);       // 32 MB bf16 weight scratch
    // wkv scratch overlays kf region (dead during TimeMix):
    float* wAb = (float*)(ws + 112 * MB);
    float* wBb = (float*)(ws + 112 * MB + 512 * 1024);
    float* wSa = (float*)(ws + 113 * MB);
    float* wSb = (float*)(ws + 113 * MB + 512 * 1024);
    // ffn_value split-K partials: 4 x 16 MB in [32,96) (xr/kb/vb/rb dead)
    float* fvp = (float*)(ws + 32 * MB);

    const int T = T_DIM, C = C_DIM, F = F_DIM;
    const dim3 blk(256), blk5(512);

    // --- TimeMix ---
    ln_mix3<<<T, blk, 0, stream>>>(x, att_shift, ln1w, ln1b, tmk, tmv, tmr, xk, xv, xr);

    // all four CxC weights in one launch: Wb = [Wk|Wv|Wr|Wo]
    cvt4_bf16<<<dim3(1024, 4), blk, 0, stream>>>(Wk, Wv, Wr, Wo, Wb, C * C / 8);
    // batched qkv: grid 16x16x3 = 768 blocks (128² kernel)
    gemm_bt<EPI_F32><<<dim3(C / 128, T / 128, 3), blk, 0, stream>>>(
        xk, C, (long)T * C, Wb, C, (long)C * C, 0, C,
        kb, C, (long)T * C, nullptr, nullptr);

    wkv_part<<<(C * WKV_P) / 256, blk, 0, stream>>>(td, kb, vb, wAb, wBb);
    wkv_comb<<<C / 256, blk, 0, stream>>>(td, wkv_state, wAb, wBb, wSa, wSb);
    wkv_emit<<<(C * WKV_P) / 256, blk, 0, stream>>>(td, tf, kb, vb, rb, wSa, wSb, pb);

    // att_out fused +x: 256 blocks (Wo already converted at Wb+3*C*C)
    gemm_bt<EPI_ADDX><<<dim3(C / 128, T / 128, 1), blk, 0, stream>>>(
        pb, C, 0, Wb + 3 * (size_t)C * C, C, 0, 0, C, x1, C, 0, x, nullptr);

    // --- ChannelMix ---
    ln_mix2<<<T, blk, 0, stream>>>(x1, ffn_shift, ln2w, ln2b, ftmk, ftmr, xk, xv);

    cvt_bf16<<<2048, blk, 0, stream>>>(Wfk, Wb, F * C / 8);
    // ffn_key on 256² 8-phase: grid 32x8 = 256 blocks
    gemm8p<EPI_RELU2><<<dim3(F / 256, T / 256, 1), blk5, 0, stream>>>(
        xk, C, Wb, C, 0, C, kf, F, 0);

    cvt_bf16<<<2048, blk, 0, stream>>>(Wfv, Wb, C * F / 8);
    // ffn_value on 256² 8-phase, split-K x4 (koff=2048): 256 blocks
    gemm8p<EPI_F32><<<dim3(C / 256, T / 256, 4), blk5, 0, stream>>>(
        kf, F, Wb, F, 2048, 2048, fvp, C, (long)T * C);
    reduce4<<<2048, blk, 0, stream>>>(fvp, fvp + (size_t)T * C, fvp + 2 * (size_t)T * C,
                                      fvp + 3 * (size_t)T * C, rx0, T * C / 4);

    cvt_bf16<<<2048, blk, 0, stream>>>(Wfr, Wb, C * C / 8);
    // ffn_recept fused sigmoid*kv+x1: 256 blocks (128² kernel)
    gemm_bt<EPI_SIGMULADD><<<dim3(C / 128, T / 128, 1), blk, 0, stream>>>(
        xv, C, 0, Wb, C, 0, 0, C, out, C, 0, x1, rx0);
}

// Round 11
// 383.623 us; speedup vs baseline: 1.0748x; 1.0117x over previous
//
#include <hip/hip_runtime.h>
#include <hip/hip_bf16.h>

typedef unsigned short u16;
typedef short bf16x8 __attribute__((ext_vector_type(8)));
typedef float f32x4 __attribute__((ext_vector_type(4)));

#define T_DIM 2048
#define C_DIM 2048
#define F_DIM 8192
#define WKV_L 32
#define WKV_P (T_DIM / WKV_L)   // 64 chunks

// ---------- helpers ----------
__device__ __forceinline__ u16 f2bf(float f) {
    unsigned int u = __float_as_uint(f);
    u += 0x7fff + ((u >> 16) & 1);          // round-to-nearest-even
    return (u16)(u >> 16);
}

__device__ __forceinline__ void async16(const void* g, void* l) {
    __builtin_amdgcn_global_load_lds(
        (__attribute__((address_space(1))) const unsigned int*)g,
        (__attribute__((address_space(3))) unsigned int*)l, 16, 0, 0);
}

// ---------- fused LayerNorm + token-shift mix (3 outputs) ----------
__global__ __launch_bounds__(256) void ln_mix3(
        const float* __restrict__ x, const float* __restrict__ sh,
        const float* __restrict__ w, const float* __restrict__ b,
        const float* __restrict__ mk, const float* __restrict__ mv,
        const float* __restrict__ mr,
        u16* __restrict__ xk, u16* __restrict__ xv, u16* __restrict__ xr) {
    __shared__ float red[16];
    const int t = blockIdx.x, tid = threadIdx.x;
    const float4* cr = (const float4*)(x + (size_t)t * C_DIM);
    float4 c0 = cr[tid * 2], c1 = cr[tid * 2 + 1];
    float s = c0.x + c0.y + c0.z + c0.w + c1.x + c1.y + c1.z + c1.w;
    float q = c0.x * c0.x + c0.y * c0.y + c0.z * c0.z + c0.w * c0.w
            + c1.x * c1.x + c1.y * c1.y + c1.z * c1.z + c1.w * c1.w;
    float4 p0, p1;
    float sp = 0.f, qp = 0.f;
    if (t > 0) {
        const float4* pr = (const float4*)(x + (size_t)(t - 1) * C_DIM);
        p0 = pr[tid * 2]; p1 = pr[tid * 2 + 1];
        sp = p0.x + p0.y + p0.z + p0.w + p1.x + p1.y + p1.z + p1.w;
        qp = p0.x * p0.x + p0.y * p0.y + p0.z * p0.z + p0.w * p0.w
           + p1.x * p1.x + p1.y * p1.y + p1.z * p1.z + p1.w * p1.w;
    } else {
        const float4* pr = (const float4*)sh;
        p0 = pr[tid * 2]; p1 = pr[tid * 2 + 1];
    }
    #pragma unroll
    for (int off = 32; off > 0; off >>= 1) {
        s += __shfl_down(s, off);   q += __shfl_down(q, off);
        sp += __shfl_down(sp, off); qp += __shfl_down(qp, off);
    }
    const int lane = tid & 63, wv = tid >> 6;
    if (lane == 0) { red[wv] = s; red[4 + wv] = q; red[8 + wv] = sp; red[12 + wv] = qp; }
    __syncthreads();
    if (tid == 0) {
        red[0] += red[1] + red[2] + red[3];
        red[4] += red[5] + red[6] + red[7];
        red[8] += red[9] + red[10] + red[11];
        red[12] += red[13] + red[14] + red[15];
    }
    __syncthreads();
    const float mc = red[0] * (1.f / C_DIM);
    const float ic = rsqrtf(red[4] * (1.f / C_DIM) - mc * mc + 1e-5f);
    const float mp = red[8] * (1.f / C_DIM);
    const float ip = rsqrtf(red[12] * (1.f / C_DIM) - mp * mp + 1e-5f);
    const float4* w4 = (const float4*)w;
    const float4* b4 = (const float4*)b;
    #pragma unroll
    for (int j = 0; j < 2; ++j) {
        const int i4 = tid * 2 + j;
        float4 cv = j ? c1 : c0, pv = j ? p1 : p0;
        float4 wv4 = w4[i4], bv = b4[i4];
        float4 cl, pl;
        cl.x = (cv.x - mc) * ic * wv4.x + bv.x;
        cl.y = (cv.y - mc) * ic * wv4.y + bv.y;
        cl.z = (cv.z - mc) * ic * wv4.z + bv.z;
        cl.w = (cv.w - mc) * ic * wv4.w + bv.w;
        if (t > 0) {
            pl.x = (pv.x - mp) * ip * wv4.x + bv.x;
            pl.y = (pv.y - mp) * ip * wv4.y + bv.y;
            pl.z = (pv.z - mp) * ip * wv4.z + bv.z;
            pl.w = (pv.w - mp) * ip * wv4.w + bv.w;
        } else pl = pv;
        const size_t o = (size_t)t * (C_DIM / 4) + i4;
        float4 m;
        ushort4 r;
        m = ((const float4*)mk)[i4];
        r.x = f2bf(cl.x * m.x + pl.x * (1.f - m.x));
        r.y = f2bf(cl.y * m.y + pl.y * (1.f - m.y));
        r.z = f2bf(cl.z * m.z + pl.z * (1.f - m.z));
        r.w = f2bf(cl.w * m.w + pl.w * (1.f - m.w));
        ((ushort4*)xk)[o] = r;
        m = ((const float4*)mv)[i4];
        r.x = f2bf(cl.x * m.x + pl.x * (1.f - m.x));
        r.y = f2bf(cl.y * m.y + pl.y * (1.f - m.y));
        r.z = f2bf(cl.z * m.z + pl.z * (1.f - m.z));
        r.w = f2bf(cl.w * m.w + pl.w * (1.f - m.w));
        ((ushort4*)xv)[o] = r;
        m = ((const float4*)mr)[i4];
        r.x = f2bf(cl.x * m.x + pl.x * (1.f - m.x));
        r.y = f2bf(cl.y * m.y + pl.y * (1.f - m.y));
        r.z = f2bf(cl.z * m.z + pl.z * (1.f - m.z));
        r.w = f2bf(cl.w * m.w + pl.w * (1.f - m.w));
        ((ushort4*)xr)[o] = r;
    }
}

// ---------- fused LayerNorm + token-shift mix (2 outputs) ----------
__global__ __launch_bounds__(256) void ln_mix2(
        const float* __restrict__ x, const float* __restrict__ sh,
        const float* __restrict__ w, const float* __restrict__ b,
        const float* __restrict__ mk, const float* __restrict__ mr,
        u16* __restrict__ fk, u16* __restrict__ fr) {
    __shared__ float red[16];
    const int t = blockIdx.x, tid = threadIdx.x;
    const float4* cr = (const float4*)(x + (size_t)t * C_DIM);
    float4 c0 = cr[tid * 2], c1 = cr[tid * 2 + 1];
    float s = c0.x + c0.y + c0.z + c0.w + c1.x + c1.y + c1.z + c1.w;
    float q = c0.x * c0.x + c0.y * c0.y + c0.z * c0.z + c0.w * c0.w
            + c1.x * c1.x + c1.y * c1.y + c1.z * c1.z + c1.w * c1.w;
    float4 p0, p1;
    float sp = 0.f, qp = 0.f;
    if (t > 0) {
        const float4* pr = (const float4*)(x + (size_t)(t - 1) * C_DIM);
        p0 = pr[tid * 2]; p1 = pr[tid * 2 + 1];
        sp = p0.x + p0.y + p0.z + p0.w + p1.x + p1.y + p1.z + p1.w;
        qp = p0.x * p0.x + p0.y * p0.y + p0.z * p0.z + p0.w * p0.w
           + p1.x * p1.x + p1.y * p1.y + p1.z * p1.z + p1.w * p1.w;
    } else {
        const float4* pr = (const float4*)sh;
        p0 = pr[tid * 2]; p1 = pr[tid * 2 + 1];
    }
    #pragma unroll
    for (int off = 32; off > 0; off >>= 1) {
        s += __shfl_down(s, off);   q += __shfl_down(q, off);
        sp += __shfl_down(sp, off); qp += __shfl_down(qp, off);
    }
    const int lane = tid & 63, wv = tid >> 6;
    if (lane == 0) { red[wv] = s; red[4 + wv] = q; red[8 + wv] = sp; red[12 + wv] = qp; }
    __syncthreads();
    if (tid == 0) {
        red[0] += red[1] + red[2] + red[3];
        red[4] += red[5] + red[6] + red[7];
        red[8] += red[9] + red[10] + red[11];
        red[12] += red[13] + red[14] + red[15];
    }
    __syncthreads();
    const float mc = red[0] * (1.f / C_DIM);
    const float ic = rsqrtf(red[4] * (1.f / C_DIM) - mc * mc + 1e-5f);
    const float mp = red[8] * (1.f / C_DIM);
    const float ip = rsqrtf(red[12] * (1.f / C_DIM) - mp * mp + 1e-5f);
    const float4* w4 = (const float4*)w;
    const float4* b4 = (const float4*)b;
    #pragma unroll
    for (int j = 0; j < 2; ++j) {
        const int i4 = tid * 2 + j;
        float4 cv = j ? c1 : c0, pv = j ? p1 : p0;
        float4 wv4 = w4[i4], bv = b4[i4];
        float4 cl, pl;
        cl.x = (cv.x - mc) * ic * wv4.x + bv.x;
        cl.y = (cv.y - mc) * ic * wv4.y + bv.y;
        cl.z = (cv.z - mc) * ic * wv4.z + bv.z;
        cl.w = (cv.w - mc) * ic * wv4.w + bv.w;
        if (t > 0) {
            pl.x = (pv.x - mp) * ip * wv4.x + bv.x;
            pl.y = (pv.y - mp) * ip * wv4.y + bv.y;
            pl.z = (pv.z - mp) * ip * wv4.z + bv.z;
            pl.w = (pv.w - mp) * ip * wv4.w + bv.w;
        } else pl = pv;
        const size_t o = (size_t)t * (C_DIM / 4) + i4;
        float4 m;
        ushort4 r;
        m = ((const float4*)mk)[i4];
        r.x = f2bf(cl.x * m.x + pl.x * (1.f - m.x));
        r.y = f2bf(cl.y * m.y + pl.y * (1.f - m.y));
        r.z = f2bf(cl.z * m.z + pl.z * (1.f - m.z));
        r.w = f2bf(cl.w * m.w + pl.w * (1.f - m.w));
        ((ushort4*)fk)[o] = r;
        m = ((const float4*)mr)[i4];
        r.x = f2bf(cl.x * m.x + pl.x * (1.f - m.x));
        r.y = f2bf(cl.y * m.y + pl.y * (1.f - m.y));
        r.z = f2bf(cl.z * m.z + pl.z * (1.f - m.z));
        r.w = f2bf(cl.w * m.w + pl.w * (1.f - m.w));
        ((ushort4*)fr)[o] = r;
    }
}

// ---------- f32 -> bf16 conversion ----------
__global__ __launch_bounds__(256) void cvt_bf16(const float* __restrict__ in,
                                                u16* __restrict__ out, int n8) {
    int i = blockIdx.x * 256 + threadIdx.x;
    const int stride = gridDim.x * 256;
    for (; i < n8; i += stride) {
        const float4* p = (const float4*)(in + (size_t)i * 8);
        float4 a = p[0], b = p[1];
        ushort4 lo, hi;
        lo.x = f2bf(a.x); lo.y = f2bf(a.y); lo.z = f2bf(a.z); lo.w = f2bf(a.w);
        hi.x = f2bf(b.x); hi.y = f2bf(b.y); hi.z = f2bf(b.z); hi.w = f2bf(b.w);
        ((ushort4*)out)[i * 2] = lo;
        ((ushort4*)out)[i * 2 + 1] = hi;
    }
}

// four C*C weights in one launch (blockIdx.y selects the array)
__global__ __launch_bounds__(256) void cvt4_bf16(const float* __restrict__ i0,
                                                 const float* __restrict__ i1,
                                                 const float* __restrict__ i2,
                                                 const float* __restrict__ i3,
                                                 u16* __restrict__ out, int n8) {
    const int sel = blockIdx.y;
    const float* in = sel == 0 ? i0 : (sel == 1 ? i1 : (sel == 2 ? i2 : i3));
    u16* o = out + (size_t)sel * n8 * 8;
    int i = blockIdx.x * 256 + threadIdx.x;
    const int stride = gridDim.x * 256;
    for (; i < n8; i += stride) {
        const float4* p = (const float4*)(in + (size_t)i * 8);
        float4 a = p[0], b = p[1];
        ushort4 lo, hi;
        lo.x = f2bf(a.x); lo.y = f2bf(a.y); lo.z = f2bf(a.z); lo.w = f2bf(a.w);
        hi.x = f2bf(b.x); hi.y = f2bf(b.y); hi.z = f2bf(b.z); hi.w = f2bf(b.w);
        ((ushort4*)o)[i * 2] = lo;
        ((ushort4*)o)[i * 2 + 1] = hi;
    }
}

// ---------- 4-way partial-sum reduce (float4) ----------
__global__ __launch_bounds__(256) void reduce4(const float* __restrict__ p0,
                                               const float* __restrict__ p1,
                                               const float* __restrict__ p2,
                                               const float* __restrict__ p3,
                                               float* __restrict__ o, int n4) {
    int i = blockIdx.x * 256 + threadIdx.x;
    const int stride = gridDim.x * 256;
    for (; i < n4; i += stride) {
        float4 a = ((const float4*)p0)[i], b = ((const float4*)p1)[i];
        float4 c = ((const float4*)p2)[i], d = ((const float4*)p3)[i];
        float4 r;
        r.x = a.x + b.x + c.x + d.x;
        r.y = a.y + b.y + c.y + d.y;
        r.z = a.z + b.z + c.z + d.z;
        r.w = a.w + b.w + c.w + d.w;
        ((float4*)o)[i] = r;
    }
}

// ---------- WKV parallel scan ----------
__global__ __launch_bounds__(256) void wkv_part(const float* __restrict__ td,
                                                const float* __restrict__ k,
                                                const float* __restrict__ v,
                                                float* __restrict__ Ab,
                                                float* __restrict__ Bb) {
    const int idx = blockIdx.x * 256 + threadIdx.x;     // C*P threads
    const int c = idx & (C_DIM - 1);
    const int p = idx >> 11;
    const float ew = expf(-expf(td[c]));
    float A = 0.f, B = 0.f;
    size_t o = (size_t)(p * WKV_L) * C_DIM + c;
    #pragma unroll 4
    for (int i = 0; i < WKV_L; ++i, o += C_DIM) {
        const float kk = expf(k[o]);
        A = (A + kk * v[o]) * ew;
        B = (B + kk) * ew;
    }
    Ab[p * C_DIM + c] = A;
    Bb[p * C_DIM + c] = B;
}

__global__ __launch_bounds__(256) void wkv_comb(const float* __restrict__ td,
                                                const float* __restrict__ st,
                                                const float* __restrict__ Ab,
                                                const float* __restrict__ Bb,
                                                float* __restrict__ Sa,
                                                float* __restrict__ Sb) {
    const int c = blockIdx.x * 256 + threadIdx.x;       // C threads
    const float w = -expf(td[c]);
    const float dL = expf(w * (float)WKV_L);            // ew^L
    float a = st[c];
    float b = st[C_DIM + c];
    #pragma unroll 4
    for (int p = 0; p < WKV_P; ++p) {
        Sa[p * C_DIM + c] = a;
        Sb[p * C_DIM + c] = b;
        a = dL * a + Ab[p * C_DIM + c];
        b = dL * b + Bb[p * C_DIM + c];
    }
}

__global__ __launch_bounds__(256) void wkv_emit(const float* __restrict__ td,
                                                const float* __restrict__ tf,
                                                const float* __restrict__ k,
                                                const float* __restrict__ v,
                                                const float* __restrict__ r,
                                                const float* __restrict__ Sa,
                                                const float* __restrict__ Sb,
                                                u16* __restrict__ pout) {
    const int idx = blockIdx.x * 256 + threadIdx.x;     // C*P threads
    const int c = idx & (C_DIM - 1);
    const int p = idx >> 11;
    const float u = tf[c];
    const float w = -expf(td[c]);
    const float ew = expf(w);
    float a = Sa[p * C_DIM + c];
    float b = Sb[p * C_DIM + c];
    size_t o = (size_t)(p * WKV_L) * C_DIM + c;
    #pragma unroll 2
    for (int i = 0; i < WKV_L; ++i, o += C_DIM) {
        const float kt = k[o], vt = v[o], rt = r[o];
        const float e = expf(u + w + kt);
        const float y = (a + e * vt) / (b + e);
        const float kk = expf(kt);
        a = (a + kk * vt) * ew;
        b = (b + kk) * ew;
        const float sr = 1.f / (1.f + expf(-rt));
        pout[o] = f2bf(sr * y);
    }
}

enum { EPI_F32 = 0, EPI_ADDX = 1, EPI_RELU2 = 2, EPI_SIGMULADD = 3 };

// ---------- 128x128 bf16 NT GEMM — 3-slot pipeline (R9, proven) ----------
template <int EPI>
__global__ __launch_bounds__(256, 3) void gemm_bt(
        const u16* __restrict__ A, int lda, long a_zs,
        const u16* __restrict__ B, int ldb, long b_zs,
        long koff, int Kloop,
        void* __restrict__ outp, int ldo, long o_zs,
        const float* __restrict__ aux1, const float* __restrict__ aux2) {
    __shared__ u16 lds[3 * 8192];   // 48 KiB: 3 slots x (A 8KB + B 8KB)
    const int tid = threadIdx.x;
    const int l = tid & 63, w = tid >> 6;
    const int wr2 = w >> 1, wc2 = w & 1;     // 2x2 waves of 64x64

    const int gx = gridDim.x, gy = gridDim.y;
    const int nxy = gx * gy;
    const int flat = (blockIdx.z * gy + blockIdx.y) * gx + blockIdx.x;
    const int cpx = (nxy * gridDim.z) >> 3;
    const int swz = (flat & 7) * cpx + (flat >> 3);
    const int z = swz / nxy;
    const int rem = swz - z * nxy;
    const int bm = rem % gy;
    const int bn = rem / gy;

    const u16* Ag = A + (size_t)z * a_zs + (size_t)z * koff + (size_t)bm * 128 * lda;
    const u16* Bg = B + (size_t)z * b_zs + (size_t)z * koff + (size_t)bn * 128 * ldb;

    long gA[2], gB[2];
    int dA[2], dB[2];
    #pragma unroll
    for (int j = 0; j < 2; ++j) {
        const int off = j * 4096 + w * 1024 + l * 16;
        const int row = off >> 6;
        const int cb = (off & 63) ^ (((off >> 9) & 1) << 5);
        gA[j] = (long)row * lda + (cb >> 1);
        gB[j] = (long)row * ldb + (cb >> 1);
        dA[j] = j * 2048 + w * 512;
        dB[j] = 4096 + j * 2048 + w * 512;
    }

    int offA[4], offB[4];
    #pragma unroll
    for (int m = 0; m < 4; ++m) {
        const int lin = (wr2 * 64 + m * 16 + (l & 15)) * 64 + ((l >> 4) << 4);
        offA[m] = (lin ^ (((lin >> 9) & 1) << 5)) >> 1;
    }
    #pragma unroll
    for (int n = 0; n < 4; ++n) {
        const int lin = (wc2 * 64 + n * 16 + (l & 15)) * 64 + ((l >> 4) << 4);
        offB[n] = 4096 + ((lin ^ (((lin >> 9) & 1) << 5)) >> 1);
    }

    const f32x4 fz = {0.f, 0.f, 0.f, 0.f};
    f32x4 acc[4][4];
    #pragma unroll
    for (int m = 0; m < 4; ++m)
        #pragma unroll
        for (int n = 0; n < 4; ++n) acc[m][n] = fz;

    const int NT = Kloop >> 5;

    auto stage = [&](int kt, int sp) {
        const long ko = (long)kt << 5;
        const int sb = sp * 8192;
        async16(Ag + gA[0] + ko, &lds[sb + dA[0]]);
        async16(Ag + gA[1] + ko, &lds[sb + dA[1]]);
        async16(Bg + gB[0] + ko, &lds[sb + dB[0]]);
        async16(Bg + gB[1] + ko, &lds[sb + dB[1]]);
    };

    stage(0, 0);
    stage(1, 1);

    int sr = 0;
    for (int t = 0; t < NT; ++t) {
        asm volatile("s_waitcnt vmcnt(4)" ::: "memory");
        __builtin_amdgcn_s_barrier();
        __builtin_amdgcn_sched_barrier(0);
        {
            const int tp = (t + 2 < NT) ? t + 2 : NT - 1;
            const int sp = (sr == 0) ? 2 : sr - 1;
            stage(tp, sp);
        }
        const int sb = sr * 8192;
        bf16x8 af[4], bfv[4];
        #pragma unroll
        for (int m = 0; m < 4; ++m) af[m] = *(const bf16x8*)&lds[sb + offA[m]];
        #pragma unroll
        for (int n = 0; n < 4; ++n) bfv[n] = *(const bf16x8*)&lds[sb + offB[n]];
        __builtin_amdgcn_s_setprio(1);
        #pragma unroll
        for (int m = 0; m < 2; ++m)
            #pragma unroll
            for (int n = 0; n < 4; ++n)
                acc[m][n] = __builtin_amdgcn_mfma_f32_16x16x32_bf16(af[m], bfv[n], acc[m][n], 0, 0, 0);
        __builtin_amdgcn_s_setprio(0);
        __builtin_amdgcn_s_setprio(1);
        #pragma unroll
        for (int m = 2; m < 4; ++m)
            #pragma unroll
            for (int n = 0; n < 4; ++n)
                acc[m][n] = __builtin_amdgcn_mfma_f32_16x16x32_bf16(af[m], bfv[n], acc[m][n], 0, 0, 0);
        __builtin_amdgcn_s_setprio(0);
        sr = (sr == 2) ? 0 : sr + 1;
    }
    asm volatile("s_waitcnt vmcnt(0)" ::: "memory");

    const int r00 = bm * 128 + wr2 * 64 + ((l >> 4) << 2);
    const int c00 = bn * 128 + wc2 * 64 + (l & 15);
    #pragma unroll
    for (int m = 0; m < 4; ++m) {
        #pragma unroll
        for (int n = 0; n < 4; ++n) {
            #pragma unroll
            for (int j = 0; j < 4; ++j) {
                const int rr = r00 + m * 16 + j;
                const int cc = c00 + n * 16;
                const size_t o = (size_t)rr * ldo + cc;
                const float val = acc[m][n][j];
                if constexpr (EPI == EPI_F32) {
                    ((float*)outp)[(size_t)z * o_zs + o] = val;
                } else if constexpr (EPI == EPI_ADDX) {
                    ((float*)outp)[o] = aux1[o] + val;
                } else if constexpr (EPI == EPI_RELU2) {
                    const float tp2 = fmaxf(val, 0.f);
                    ((u16*)outp)[o] = f2bf(tp2 * tp2);
                } else {  // EPI_SIGMULADD
                    const float sg = 1.f / (1.f + expf(-val));
                    ((float*)outp)[o] = aux1[o] + sg * aux2[o];
                }
            }
        }
    }
}

// ---------- 256x256 bf16 NT GEMM — 8-phase, counted vmcnt, FULL swizzle ----
// BM=BN=256, BK=64, 512 thr = 8 waves (2M x 4N; per-wave 128x64 out).
// LDS 128 KiB = 2 buffers x (A 32KB + B 32KB); 128B rows.
// FULL XOR swizzle (R11): byte ^= ((byte>>7)&7)<<4 — bank-bits [6:4] keyed on
// row-bits [2:0]. Spreads a wave's 64 ds_read_b128 lanes uniformly over all
// 32 banks (8 lanes/16B-slot = the 8-cycle minimum). Involution (key bits
// untouched). ks=1 access = swizzled offset XOR 32 elems (swz(lin+64) =
// swz(lin)^64: bit6 flips with no carry, key unchanged).
// Pipeline identical to R10 (verified): 4 phases per K-tile, vmcnt(2) only at
// phases 4 & 8, never drained in-loop.
template <int EPI>
__global__ __launch_bounds__(512, 2) void gemm8p(
        const u16* __restrict__ A, int lda,
        const u16* __restrict__ B, int ldb,
        long koff, int Kloop,
        void* __restrict__ outp, int ldo, long o_zs) {
    __shared__ u16 lds[65536];   // 128 KiB
    const int tid = threadIdx.x;
    const int l = tid & 63, w = tid >> 6;
    const int wm = w >> 2, wn = w & 3;

    const int gx = gridDim.x, gy = gridDim.y;
    const int nxy = gx * gy;
    const int flat = (blockIdx.z * gy + blockIdx.y) * gx + blockIdx.x;
    const int cpx = (nxy * gridDim.z) >> 3;
    const int swz = (flat & 7) * cpx + (flat >> 3);
    const int z = swz / nxy;
    const int rem = swz - z * nxy;
    const int bm = rem % gy;
    const int bn = rem / gy;

    const u16* Ag = A + (size_t)z * koff + (size_t)bm * 256 * lda;
    const u16* Bg = B + (size_t)z * koff + (size_t)bn * 256 * ldb;

    // staging: linear LDS dest, pre-(full-)swizzled global source.
    long srcA[4], srcB[4];
    int dst[4];
    #pragma unroll
    for (int hj = 0; hj < 4; ++hj) {
        const int off = (hj >> 1) * 16384 + (hj & 1) * 8192 + w * 1024 + l * 16;
        const int e = off ^ (((off >> 7) & 7) << 4);
        srcA[hj] = (long)(e >> 7) * lda + ((e & 127) >> 1);
        srcB[hj] = (long)(e >> 7) * ldb + ((e & 127) >> 1);
        dst[hj] = off >> 1;              // local elem index within region
    }

    // ds_read offsets at ks=0 (ks=1: offset XOR 32 elems)
    int offA[2][4], offB0[4];
    #pragma unroll
    for (int mh = 0; mh < 2; ++mh)
        #pragma unroll
        for (int mi = 0; mi < 4; ++mi) {
            const int row = wm * 128 + (mh * 4 + mi) * 16 + (l & 15);
            const int lin = row * 128 + ((l >> 4) << 4);
            offA[mh][mi] = (lin ^ (((lin >> 7) & 7) << 4)) >> 1;
        }
    #pragma unroll
    for (int n = 0; n < 4; ++n) {
        const int row = wn * 64 + n * 16 + (l & 15);
        const int lin = row * 128 + ((l >> 4) << 4);
        offB0[n] = 16384 + ((lin ^ (((lin >> 7) & 7) << 4)) >> 1);
    }

    const f32x4 fz = {0.f, 0.f, 0.f, 0.f};
    f32x4 acc[8][4];
    #pragma unroll
    for (int m = 0; m < 8; ++m)
        #pragma unroll
        for (int n = 0; n < 4; ++n) acc[m][n] = fz;

    const int NT = Kloop >> 6;          // K-tiles of 64
    const int NP = NT >> 1;             // buffer pairs

    auto stgA = [&](int kt, int buf, int h) {
        const long ko = (long)kt << 6;
        #pragma unroll
        for (int j = 0; j < 2; ++j)
            async16(Ag + srcA[h * 2 + j] + ko, &lds[buf * 32768 + dst[h * 2 + j]]);
    };
    auto stgB = [&](int kt, int buf, int h) {
        const long ko = (long)kt << 6;
        #pragma unroll
        for (int j = 0; j < 2; ++j)
            async16(Bg + srcB[h * 2 + j] + ko, &lds[buf * 32768 + 16384 + dst[h * 2 + j]]);
    };

#define PH_OPEN() __builtin_amdgcn_s_barrier(); \
    asm volatile("s_waitcnt lgkmcnt(0)" ::: "memory"); \
    __builtin_amdgcn_sched_barrier(0)
#define QUAD(af, bf, MO) \
    __builtin_amdgcn_s_setprio(1); \
    _Pragma("unroll") \
    for (int mi = 0; mi < 4; ++mi) \
        _Pragma("unroll") \
        for (int n = 0; n < 4; ++n) \
            acc[MO + mi][n] = __builtin_amdgcn_mfma_f32_16x16x32_bf16((af)[mi], (bf)[n], acc[MO + mi][n], 0, 0, 0); \
    __builtin_amdgcn_s_setprio(0)

    // prologue: buf0 <- kt0 (4 halves), buf1 <- kt1 A-half0. 10 loads.
    stgA(0, 0, 0); stgA(0, 0, 1); stgB(0, 0, 0); stgB(0, 0, 1);
    stgA(1, 1, 0);
    asm volatile("s_waitcnt vmcnt(2)" ::: "memory");   // buf0 landed
    __builtin_amdgcn_s_barrier();

    for (int p = 0; p < NP; ++p) {
        const int kt1 = 2 * p + 1;
        const int kn0 = (2 * p + 2 < NT) ? 2 * p + 2 : NT - 1;  // clamped tail
        const int kn1 = (2 * p + 3 < NT) ? 2 * p + 3 : NT - 1;
        bf16x8 a0[4], a1[4], a0k[4], a1k[4], bb[4];
        // ===== buf0 (kt=2p) =====
        // ph0: reads A-mh0-ks0 + B-ks0; stage buf1.A-h1 (kt1)
        #pragma unroll
        for (int mi = 0; mi < 4; ++mi) a0[mi] = *(const bf16x8*)&lds[offA[0][mi]];
        #pragma unroll
        for (int n = 0; n < 4; ++n) bb[n] = *(const bf16x8*)&lds[offB0[n]];
        stgA(kt1, 1, 1);
        PH_OPEN(); QUAD(a0, bb, 0);
        __builtin_amdgcn_s_barrier();
        // ph1: reads A-mh1-ks0 + A-mh0-ks1; stage buf1.B-h0 (kt1)
        #pragma unroll
        for (int mi = 0; mi < 4; ++mi) a1[mi] = *(const bf16x8*)&lds[offA[1][mi]];
        #pragma unroll
        for (int mi = 0; mi < 4; ++mi) a0k[mi] = *(const bf16x8*)&lds[offA[0][mi] ^ 32];
        stgB(kt1, 1, 0);
        PH_OPEN(); QUAD(a1, bb, 4);
        __builtin_amdgcn_s_barrier();
        // ph2: reads B-ks1 + A-mh1-ks1; stage buf1.B-h1 (kt1)
        #pragma unroll
        for (int n = 0; n < 4; ++n) bb[n] = *(const bf16x8*)&lds[offB0[n] ^ 32];
        #pragma unroll
        for (int mi = 0; mi < 4; ++mi) a1k[mi] = *(const bf16x8*)&lds[offA[1][mi] ^ 32];
        stgB(kt1, 1, 1);
        PH_OPEN(); QUAD(a0k, bb, 0);
        __builtin_amdgcn_s_barrier();
        // ph3: no reads; stage buf0.A-h0 (kn0); checkpoint vmcnt(2)
        stgA(kn0, 0, 0);
        PH_OPEN(); QUAD(a1k, bb, 4);
        asm volatile("s_waitcnt vmcnt(2)" ::: "memory");  // buf1 (kt1) landed
        __builtin_amdgcn_s_barrier();
        // ===== buf1 (kt=2p+1) =====
        // ph4
        #pragma unroll
        for (int mi = 0; mi < 4; ++mi) a0[mi] = *(const bf16x8*)&lds[32768 + offA[0][mi]];
        #pragma unroll
        for (int n = 0; n < 4; ++n) bb[n] = *(const bf16x8*)&lds[32768 + offB0[n]];
        stgA(kn0, 0, 1);
        PH_OPEN(); QUAD(a0, bb, 0);
        __builtin_amdgcn_s_barrier();
        // ph5
        #pragma unroll
        for (int mi = 0; mi < 4; ++mi) a1[mi] = *(const bf16x8*)&lds[32768 + offA[1][mi]];
        #pragma unroll
        for (int mi = 0; mi < 4; ++mi) a0k[mi] = *(const bf16x8*)&lds[32768 + (offA[0][mi] ^ 32)];
        stgB(kn0, 0, 0);
        PH_OPEN(); QUAD(a1, bb, 4);
        __builtin_amdgcn_s_barrier();
        // ph6
        #pragma unroll
        for (int n = 0; n < 4; ++n) bb[n] = *(const bf16x8*)&lds[32768 + (offB0[n] ^ 32)];
        #pragma unroll
        for (int mi = 0; mi < 4; ++mi) a1k[mi] = *(const bf16x8*)&lds[32768 + (offA[1][mi] ^ 32)];
        stgB(kn0, 0, 1);
        PH_OPEN(); QUAD(a0k, bb, 0);
        __builtin_amdgcn_s_barrier();
        // ph7: stage buf1.A-h0 (kn1); checkpoint vmcnt(2)
        stgA(kn1, 1, 0);
        PH_OPEN(); QUAD(a1k, bb, 4);
        asm volatile("s_waitcnt vmcnt(2)" ::: "memory");  // buf0 (kn0) landed
        __builtin_amdgcn_s_barrier();
    }
    asm volatile("s_waitcnt vmcnt(0)" ::: "memory");  // drain clamped tail

#undef PH_OPEN
#undef QUAD

    // --- epilogue (verified 256²/8-wave mapping) ---
    const int r00 = bm * 256 + wm * 128 + ((l >> 4) << 2);
    const int c00 = bn * 256 + wn * 64 + (l & 15);
    #pragma unroll
    for (int m = 0; m < 8; ++m) {
        #pragma unroll
        for (int n = 0; n < 4; ++n) {
            #pragma unroll
            for (int j = 0; j < 4; ++j) {
                const int rr = r00 + m * 16 + j;
                const int cc = c00 + n * 16;
                const size_t o = (size_t)rr * ldo + cc;
                const float val = acc[m][n][j];
                if constexpr (EPI == EPI_F32) {
                    ((float*)outp)[(size_t)z * o_zs + o] = val;
                } else {  // EPI_RELU2
                    const float tp2 = fmaxf(val, 0.f);
                    ((u16*)outp)[o] = f2bf(tp2 * tp2);
                }
            }
        }
    }
}

// ---------- launcher ----------
extern "C" void kernel_launch(void* const* d_in, const int* in_sizes, int n_in,
                              void* d_out, int out_size, void* d_ws, size_t ws_size,
                              hipStream_t stream) {
    const float* x         = (const float*)d_in[0];
    const float* att_shift = (const float*)d_in[1];
    const float* wkv_state = (const float*)d_in[2];
    const float* ffn_shift = (const float*)d_in[3];
    const float* ln1w = (const float*)d_in[4];
    const float* ln1b = (const float*)d_in[5];
    const float* ln2w = (const float*)d_in[6];
    const float* ln2b = (const float*)d_in[7];
    const float* tmk  = (const float*)d_in[8];
    const float* tmv  = (const float*)d_in[9];
    const float* tmr  = (const float*)d_in[10];
    const float* td   = (const float*)d_in[11];
    const float* tf   = (const float*)d_in[12];
    const float* Wk   = (const float*)d_in[13];
    const float* Wv   = (const float*)d_in[14];
    const float* Wr   = (const float*)d_in[15];
    const float* Wo   = (const float*)d_in[16];
    const float* ftmk = (const float*)d_in[17];
    const float* ftmr = (const float*)d_in[18];
    const float* Wfk  = (const float*)d_in[19];   // [F, C]
    const float* Wfv  = (const float*)d_in[20];   // [C, F]
    const float* Wfr  = (const float*)d_in[21];   // [C, C]
    float* out = (float*)d_out;

    char* ws = (char*)d_ws;
    const size_t MB = 1ull << 20;
    float* rx0 = (float*)(ws + 0);            // 16 MB f32 (reduced kv)
    u16*   xk  = (u16*)(ws + 16 * MB);        // 8 MB bf16       (also fk)
    u16*   xv  = (u16*)(ws + 24 * MB);        // 8 MB bf16       (also fr)
    u16*   xr  = (u16*)(ws + 32 * MB);        // 8 MB bf16
    float* kb  = (float*)(ws + 40 * MB);      // 16 MB f32
    float* vb  = (float*)(ws + 56 * MB);      // 16 MB f32
    float* rb  = (float*)(ws + 72 * MB);      // 16 MB f32
    u16*   pb  = (u16*)(ws + 88 * MB);        // 8 MB bf16
    float* x1  = (float*)(ws + 96 * MB);      // 16 MB f32
    u16*   kf  = (u16*)(ws + 112 * MB);       // 32 MB bf16 [T,F]
    u16*   Wb  = (u16*)(ws + 144 * MB);       // 32 MB bf16 weight scratch
    // wkv scratch overlays kf region (dead during TimeMix):
    float* wAb = (float*)(ws + 112 * MB);
    float* wBb = (float*)(ws + 112 * MB + 512 * 1024);
    float* wSa = (float*)(ws + 113 * MB);
    float* wSb = (float*)(ws + 113 * MB + 512 * 1024);
    // ffn_value split-K partials: 4 x 16 MB in [32,96) (xr/kb/vb/rb dead)
    float* fvp = (float*)(ws + 32 * MB);

    const int T = T_DIM, C = C_DIM, F = F_DIM;
    const dim3 blk(256), blk5(512);

    // --- TimeMix ---
    ln_mix3<<<T, blk, 0, stream>>>(x, att_shift, ln1w, ln1b, tmk, tmv, tmr, xk, xv, xr);

    // all four CxC weights in one launch: Wb = [Wk|Wv|Wr|Wo]
    cvt4_bf16<<<dim3(1024, 4), blk, 0, stream>>>(Wk, Wv, Wr, Wo, Wb, C * C / 8);
    // batched qkv: grid 16x16x3 = 768 blocks (128² kernel)
    gemm_bt<EPI_F32><<<dim3(C / 128, T / 128, 3), blk, 0, stream>>>(
        xk, C, (long)T * C, Wb, C, (long)C * C, 0, C,
        kb, C, (long)T * C, nullptr, nullptr);

    wkv_part<<<(C * WKV_P) / 256, blk, 0, stream>>>(td, kb, vb, wAb, wBb);
    wkv_comb<<<C / 256, blk, 0, stream>>>(td, wkv_state, wAb, wBb, wSa, wSb);
    wkv_emit<<<(C * WKV_P) / 256, blk, 0, stream>>>(td, tf, kb, vb, rb, wSa, wSb, pb);

    // att_out fused +x: 256 blocks (Wo already converted at Wb+3*C*C)
    gemm_bt<EPI_ADDX><<<dim3(C / 128, T / 128, 1), blk, 0, stream>>>(
        pb, C, 0, Wb + 3 * (size_t)C * C, C, 0, 0, C, x1, C, 0, x, nullptr);

    // --- ChannelMix ---
    ln_mix2<<<T, blk, 0, stream>>>(x1, ffn_shift, ln2w, ln2b, ftmk, ftmr, xk, xv);

    cvt_bf16<<<2048, blk, 0, stream>>>(Wfk, Wb, F * C / 8);
    // ffn_key on 256² 8-phase: grid 32x8 = 256 blocks
    gemm8p<EPI_RELU2><<<dim3(F / 256, T / 256, 1), blk5, 0, stream>>>(
        xk, C, Wb, C, 0, C, kf, F, 0);

    cvt_bf16<<<2048, blk, 0, stream>>>(Wfv, Wb, C * F / 8);
    // ffn_value on 256² 8-phase, split-K x4 (koff=2048): 256 blocks
    gemm8p<EPI_F32><<<dim3(C / 256, T / 256, 4), blk5, 0, stream>>>(
        kf, F, Wb, F, 2048, 2048, fvp, C, (long)T * C);
    reduce4<<<2048, blk, 0, stream>>>(fvp, fvp + (size_t)T * C, fvp + 2 * (size_t)T * C,
                                      fvp + 3 * (size_t)T * C, rx0, T * C / 4);

    cvt_bf16<<<2048, blk, 0, stream>>>(Wfr, Wb, C * C / 8);
    // ffn_recept fused sigmoid*kv+x1: 256 blocks (128² kernel)
    gemm_bt<EPI_SIGMULADD><<<dim3(C / 128, T / 128, 1), blk, 0, stream>>>(
        xv, C, 0, Wb, C, 0, 0, C, out, C, 0, x1, rx0);
}